// Round 6
// baseline (134.557 us; speedup 1.0000x reference)
//
#include <hip/hip_runtime.h>
#include <hip/hip_bf16.h>

// Problem constants
#define XH   64
#define XW   64
#define CIN  256
#define COUT 256
#define BATCH 4
#define KK9  9
#define M_TOT 16384      // BATCH*XH*XW
#define K_TOT 2304       // KK9*CIN
#define NKSTEP 36        // K_TOT/64

typedef __attribute__((ext_vector_type(8))) short short8;
typedef __attribute__((ext_vector_type(4))) short short4v;
typedef __attribute__((ext_vector_type(4))) float f32x4;

// Workspace layout (bytes)
#define OM_OFF   0
#define OM_BYTES (BATCH*27*4096*4)            // 1,769,472
#define XT_OFF   (OM_OFF + OM_BYTES)
#define XT_BYTES (BATCH*4096*CIN*4)           // 16,777,216
#define WT_OFF   (XT_OFF + XT_BYTES)
#define WT_BYTES (COUT*K_TOT*2)               // 1,179,648  ([tk][256o][64k])
#define WOT_OFF  (WT_OFF + WT_BYTES)
#define WOT_BYTES (36*32*64*2)                // 147,456

__device__ __forceinline__ void async16(const void* g, void* l) {
  __builtin_amdgcn_global_load_lds((const __attribute__((address_space(1))) void*)g,
                                   (__attribute__((address_space(3))) void*)l,
                                   16, 0, 0);
}

// ---------------------------------------------------------------------------
// K0: w_conv (O,C,3,3) f32 -> Wt2 tiled bf16: [tk(36)][256 o][64 k],
//     k = kk*256 + c
// ---------------------------------------------------------------------------
__global__ __launch_bounds__(256) void k0_wt(const float* __restrict__ wconv,
                                             __hip_bfloat16* __restrict__ Wt2) {
  int e = blockIdx.x * 256 + threadIdx.x;      // < 36*16384 = 589824
  int tk = e >> 14;
  int r  = e & 16383;
  int o  = r >> 6, kl = r & 63;
  int k  = tk * 64 + kl;
  int kk = k >> 8, c = k & 255;
  float v = wconv[(o * CIN + c) * KK9 + kk];
  Wt2[e] = __float2bfloat16(v);
}

// ---------------------------------------------------------------------------
// K0b: w_off (27,C,3,3) f32 -> Wot tiled bf16: [tk(36)][32 oc][64 k]
// ---------------------------------------------------------------------------
__global__ __launch_bounds__(256) void k0b_wot(const float* __restrict__ woff,
                                               __hip_bfloat16* __restrict__ Wot) {
  int e = blockIdx.x * 256 + threadIdx.x;      // < 36*2048 = 73728
  int tk = e >> 11;
  int r  = e & 2047;
  int ocl = r >> 6, kl = r & 63;
  int k = tk * 64 + kl;
  int kk = k >> 8, c = k & 255;
  float v = (ocl < 27) ? woff[((size_t)(ocl * 256 + c)) * 9 + kk] : 0.f;
  Wot[e] = __float2bfloat16(v);
}

// ---------------------------------------------------------------------------
// KT: transpose x (B,C,H,W) f32 -> xT[b][hw][c] f32
// ---------------------------------------------------------------------------
__global__ __launch_bounds__(256) void kt_xt(const float* __restrict__ x,
                                             float* __restrict__ xT) {
  __shared__ float t[64][65];
  int blk = blockIdx.x;
  int hwg = blk & 63;
  int cg  = (blk >> 6) & 3;
  int b   = blk >> 8;
  int hw0 = hwg * 64, c0 = cg * 64;
  int l = threadIdx.x & 63, q = threadIdx.x >> 6;
  const float* xb = x + ((size_t)(b * 256 + c0) << 12) + hw0;
#pragma unroll
  for (int i = 0; i < 16; ++i) {
    int cl = q * 16 + i;
    t[cl][l] = xb[((size_t)cl << 12) + l];
  }
  __syncthreads();
  float* xTb = xT + (((size_t)b << 12) + hw0) * 256 + c0;
#pragma unroll
  for (int i = 0; i < 16; ++i) {
    int hwl = q * 16 + i;
    xTb[(size_t)hwl * 256 + l] = t[l][hwl];
  }
}

// ---------------------------------------------------------------------------
// K1: offset conv as MFMA GEMM (64 m x 32 oc per block, grid 256).
// ---------------------------------------------------------------------------
__global__ __launch_bounds__(256) void k1_omgemm(const float* __restrict__ xT,
                                                 const __hip_bfloat16* __restrict__ Wot,
                                                 const float* __restrict__ boff,
                                                 float* __restrict__ om) {
  __shared__ __align__(16) __hip_bfloat16 sP[64 * 64];
  __shared__ __align__(16) __hip_bfloat16 sWo[32 * 64];
  int tm = blockIdx.x;
  int tid = threadIdx.x;
  int wv = tid >> 6, lane = tid & 63;
  int lo = lane & 15, hi = lane >> 4;

  int r0 = tid >> 3;            // 0..31
  int kb = (tid & 7) * 8;       // 0..56

  f32x4 zero4 = {0.f, 0.f, 0.f, 0.f};
  f32x4 acc[2] = {zero4, zero4};

  for (int tk = 0; tk < NKSTEP; ++tk) {
    async16((const char*)Wot + (size_t)tk * 4096 + tid * 16, (char*)sWo + tid * 16);

    int kk = tk >> 2, cc = tk & 3;
    int ky = kk / 3, kx = kk - ky * 3;
#pragma unroll
    for (int half = 0; half < 2; ++half) {
      int row = r0 + half * 32;
      int m_s = tm * 64 + row;
      int b_s = m_s >> 12, hw_s = m_s & 4095, h_s = hw_s >> 6, w_s = hw_s & 63;
      int yy = h_s + ky - 1, xx = w_s + kx - 1;
      bool valid = ((unsigned)yy < 64u) && ((unsigned)xx < 64u);
      short8 h8 = {0, 0, 0, 0, 0, 0, 0, 0};
      if (valid) {
        const float* src = xT + ((((size_t)b_s << 12) + yy * 64 + xx) << 8) + cc * 64 + kb;
        f32x4 u0 = *(const f32x4*)src;
        f32x4 u1 = *(const f32x4*)(src + 4);
        __hip_bfloat16 tmp[8];
#pragma unroll
        for (int j = 0; j < 4; ++j) {
          tmp[j]     = __float2bfloat16(u0[j]);
          tmp[4 + j] = __float2bfloat16(u1[j]);
        }
        h8 = *(const short8*)tmp;
      }
      *(short8*)&sP[row * 64 + kb] = h8;
    }
    __syncthreads();

    short8 bfr[2], a[2][2];
#pragma unroll
    for (int kc = 0; kc < 2; ++kc) {
      bfr[kc] = *(const short8*)&sP[(wv * 16 + lo) * 64 + kc * 32 + hi * 8];
#pragma unroll
      for (int f = 0; f < 2; ++f)
        a[f][kc] = *(const short8*)&sWo[(f * 16 + lo) * 64 + kc * 32 + hi * 8];
    }
#pragma unroll
    for (int f = 0; f < 2; ++f)
#pragma unroll
      for (int kc = 0; kc < 2; ++kc)
        acc[f] = __builtin_amdgcn_mfma_f32_16x16x32_bf16(a[f][kc], bfr[kc], acc[f], 0, 0, 0);
    __syncthreads();
  }

  int m_o = tm * 64 + wv * 16 + lo;
  int b_o = m_o >> 12, hw_o = m_o & 4095;
#pragma unroll
  for (int f = 0; f < 2; ++f) {
#pragma unroll
    for (int r = 0; r < 4; ++r) {
      int oc = f * 16 + hi * 4 + r;
      if (oc < 27)
        om[(((size_t)(b_o * 27 + oc)) << 12) + hw_o] = acc[f][r] + boff[oc];
    }
  }
}

// ---------------------------------------------------------------------------
// K23: fused deformable-gather + GEMM.
// Block tile: 64 m x 256 o, grid 256 (tm). 256 thr (4 waves; wave wv owns
// o in [wv*64, wv*64+64)).  Per K-step (tk = kk*4+cc):
//   stage sW (32KB) via global_load_lds; build sV[64m][64k] by bilinear
//   gather from xT using per-(row,kk) params precomputed in LDS.
// ---------------------------------------------------------------------------
__global__ __launch_bounds__(256) void k23_fused(const float* __restrict__ xT,
                                                 const float* __restrict__ om,
                                                 const __hip_bfloat16* __restrict__ Wt2,
                                                 float* __restrict__ out) {
  __shared__ __align__(16) __hip_bfloat16 sW[256 * 64];   // 32 KB
  __shared__ __align__(16) __hip_bfloat16 sV[64 * 64];    // 8 KB
  __shared__ float sw00[576], sw01[576], sw10[576], sw11[576];
  __shared__ int   so00[576], so01[576], so10[576], so11[576];

  int tm = blockIdx.x;          // 0..255
  int tid = threadIdx.x;
  int wv = tid >> 6, lane = tid & 63;
  int lo = lane & 15, hi = lane >> 4;
  int b = tm >> 6;              // batch constant per block (64 | 4096)
  int m0 = tm * 64;

  // ---- prologue: gather params for (row 0..63) x (kk 0..8) ----
  for (int it = tid; it < 576; it += 256) {
    int kk = it >> 6, row = it & 63;
    int m = m0 + row;
    int hw = m & 4095, h = hw >> 6, w = hw & 63;
    const float* omb = om + ((size_t)(b * 27) << 12) + hw;
    float dy = omb[(size_t)(2 * kk) << 12];
    float dx = omb[(size_t)(2 * kk + 1) << 12];
    float mz = omb[(size_t)(18 + kk) << 12];
    int ky = kk / 3, kx = kk - ky * 3;
    float py = dy + (float)(h - 1 + ky);
    float px = dx + (float)(w - 1 + kx);
    float y0f = floorf(py), x0f = floorf(px);
    float wy = py - y0f, wx = px - x0f;
    int y0 = (int)y0f, x0 = (int)x0f;
    bool vy0 = (unsigned)y0 < 64u, vy1 = (unsigned)(y0 + 1) < 64u;
    bool vx0 = (unsigned)x0 < 64u, vx1 = (unsigned)(x0 + 1) < 64u;
    int cy0 = min(max(y0, 0), 63), cy1 = min(max(y0 + 1, 0), 63);
    int cx0 = min(max(x0, 0), 63), cx1 = min(max(x0 + 1, 0), 63);
    float mask = 1.f / (1.f + __expf(-mz));
    sw00[it] = (vy0 && vx0) ? (1.f - wy) * (1.f - wx) * mask : 0.f;
    sw01[it] = (vy0 && vx1) ? (1.f - wy) * wx * mask : 0.f;
    sw10[it] = (vy1 && vx0) ? wy * (1.f - wx) * mask : 0.f;
    sw11[it] = (vy1 && vx1) ? wy * wx * mask : 0.f;
    so00[it] = cy0 * 64 + cx0;
    so01[it] = cy0 * 64 + cx1;
    so10[it] = cy1 * 64 + cx0;
    so11[it] = cy1 * 64 + cx1;
  }
  __syncthreads();

  f32x4 zero4 = {0.f, 0.f, 0.f, 0.f};
  f32x4 acc[4][4];              // [fo][fm]
#pragma unroll
  for (int fo = 0; fo < 4; ++fo)
#pragma unroll
    for (int fm = 0; fm < 4; ++fm) acc[fo][fm] = zero4;

  const float* xb = xT + (((size_t)b << 12) << 8);
  int vrow0 = tid >> 4;         // 0..15
  int chq   = tid & 15;

  for (int tk = 0; tk < NKSTEP; ++tk) {
    // stage W tile [256o][64k] = 32KB
#pragma unroll
    for (int j = 0; j < 8; ++j) {
      int off = (j * 256 + tid) * 16;
      async16((const char*)Wt2 + (size_t)tk * 32768 + off, (char*)sW + off);
    }
    int kk = tk >> 2, cc = tk & 3;
    // build V tile [64m][64k]: 4 passes of 16 rows
#pragma unroll
    for (int p = 0; p < 4; ++p) {
      int row = vrow0 + p * 16;
      int it = kk * 64 + row;
      const float* base = xb + cc * 64 + chq * 4;
      f32x4 t00 = *(const f32x4*)(base + ((size_t)so00[it] << 8));
      f32x4 t01 = *(const f32x4*)(base + ((size_t)so01[it] << 8));
      f32x4 t10 = *(const f32x4*)(base + ((size_t)so10[it] << 8));
      f32x4 t11 = *(const f32x4*)(base + ((size_t)so11[it] << 8));
      float a00 = sw00[it], a01 = sw01[it], a10 = sw10[it], a11 = sw11[it];
      __hip_bfloat16 h4[4];
#pragma unroll
      for (int j = 0; j < 4; ++j) {
        float v = a00 * t00[j] + a01 * t01[j] + a10 * t10[j] + a11 * t11[j];
        h4[j] = __float2bfloat16(v);
      }
      *(short4v*)&sV[row * 64 + chq * 4] = *(const short4v*)h4;
    }
    __syncthreads();

    short8 bfr[4][2];
#pragma unroll
    for (int fm = 0; fm < 4; ++fm)
#pragma unroll
      for (int kc = 0; kc < 2; ++kc)
        bfr[fm][kc] = *(const short8*)&sV[(fm * 16 + lo) * 64 + kc * 32 + hi * 8];

#pragma unroll
    for (int fo = 0; fo < 4; ++fo) {
      short8 a0 = *(const short8*)&sW[(wv * 64 + fo * 16 + lo) * 64 + hi * 8];
      short8 a1 = *(const short8*)&sW[(wv * 64 + fo * 16 + lo) * 64 + 32 + hi * 8];
#pragma unroll
      for (int fm = 0; fm < 4; ++fm) {
        acc[fo][fm] = __builtin_amdgcn_mfma_f32_16x16x32_bf16(a0, bfr[fm][0], acc[fo][fm], 0, 0, 0);
        acc[fo][fm] = __builtin_amdgcn_mfma_f32_16x16x32_bf16(a1, bfr[fm][1], acc[fo][fm], 0, 0, 0);
      }
    }
    __syncthreads();
  }

  // epilogue: C layout col = lane&15 -> m, row = hi*4+r -> o
  int hwbase = m0 & 4095;
#pragma unroll
  for (int fo = 0; fo < 4; ++fo) {
    int o = wv * 64 + fo * 16 + hi * 4;
#pragma unroll
    for (int fm = 0; fm < 4; ++fm) {
      int mloc = hwbase + fm * 16 + lo;
#pragma unroll
      for (int r = 0; r < 4; ++r)
        out[((size_t)(b * 256 + o + r)) * 4096 + mloc] = acc[fo][fm][r];
    }
  }
}

// ---------------------------------------------------------------------------
extern "C" void kernel_launch(void* const* d_in, const int* in_sizes, int n_in,
                              void* d_out, int out_size, void* d_ws, size_t ws_size,
                              hipStream_t stream) {
  (void)in_sizes; (void)n_in; (void)out_size; (void)ws_size;
  const float* x     = (const float*)d_in[0];
  const float* woff  = (const float*)d_in[1];
  const float* boff  = (const float*)d_in[2];
  const float* wconv = (const float*)d_in[3];
  char* ws = (char*)d_ws;
  float* om   = (float*)(ws + OM_OFF);
  float* xT   = (float*)(ws + XT_OFF);
  __hip_bfloat16* Wt2 = (__hip_bfloat16*)(ws + WT_OFF);
  __hip_bfloat16* Wot = (__hip_bfloat16*)(ws + WOT_OFF);
  float* out = (float*)d_out;

  hipLaunchKernelGGL(k0_wt,     dim3(2304), dim3(256), 0, stream, wconv, Wt2);
  hipLaunchKernelGGL(k0b_wot,   dim3(288),  dim3(256), 0, stream, woff, Wot);
  hipLaunchKernelGGL(kt_xt,     dim3(1024), dim3(256), 0, stream, x, xT);
  hipLaunchKernelGGL(k1_omgemm, dim3(256),  dim3(256), 0, stream, xT, Wot, boff, om);
  hipLaunchKernelGGL(k23_fused, dim3(256),  dim3(256), 0, stream, xT, om, Wt2, out);
}

// Round 7
// 119.375 us; speedup vs baseline: 1.1272x; 1.1272x over previous
//
#include <hip/hip_runtime.h>
#include <hip/hip_bf16.h>

// Problem constants
#define XH   64
#define XW   64
#define CIN  256
#define COUT 256
#define BATCH 4
#define KK9  9
#define M_TOT 16384      // BATCH*XH*XW
#define K_TOT 2304       // KK9*CIN
#define NKSTEP 36        // K_TOT/64

typedef __attribute__((ext_vector_type(8))) short short8;
typedef __attribute__((ext_vector_type(4))) short short4v;
typedef __attribute__((ext_vector_type(4))) float f32x4;

// Workspace layout (bytes)
#define OM_OFF   0
#define OM_BYTES (BATCH*27*4096*4)            // 1,769,472
#define XT_OFF   (OM_OFF + OM_BYTES)
#define XT_BYTES (BATCH*4096*CIN*4)           // 16,777,216
#define WT_OFF   (XT_OFF + XT_BYTES)
#define WT_BYTES (COUT*K_TOT*2)               // 1,179,648  ([tk][256o][64k], XOR-swizzled)
#define WOT_OFF  (WT_OFF + WT_BYTES)
#define WOT_BYTES (36*32*64*2)                // 147,456

__device__ __forceinline__ void async16(const void* g, void* l) {
  __builtin_amdgcn_global_load_lds((const __attribute__((address_space(1))) void*)g,
                                   (__attribute__((address_space(3))) void*)l,
                                   16, 0, 0);
}

// ---------------------------------------------------------------------------
// K0: w_conv (O,C,3,3) f32 -> Wt2 tiled bf16: [tk(36)][256 o][64 j] with
// j = k_local ^ ((o&7)<<3)  (pre-swizzled source so LDS ds_read can XOR-
// deswizzle; global_load_lds stages linearly — rule: swizzle source+read).
// ---------------------------------------------------------------------------
__global__ __launch_bounds__(256) void k0_wt(const float* __restrict__ wconv,
                                             __hip_bfloat16* __restrict__ Wt2) {
  int e = blockIdx.x * 256 + threadIdx.x;      // < 36*16384 = 589824
  int tk = e >> 14;
  int r  = e & 16383;
  int o  = r >> 6, j = r & 63;
  int kl = j ^ ((o & 7) << 3);                 // logical k within tile
  int k  = tk * 64 + kl;
  int kk = k >> 8, c = k & 255;
  float v = wconv[(o * CIN + c) * KK9 + kk];
  Wt2[e] = __float2bfloat16(v);
}

// ---------------------------------------------------------------------------
// K0b: w_off (27,C,3,3) f32 -> Wot tiled bf16: [tk(36)][32 oc][64 k]
// ---------------------------------------------------------------------------
__global__ __launch_bounds__(256) void k0b_wot(const float* __restrict__ woff,
                                               __hip_bfloat16* __restrict__ Wot) {
  int e = blockIdx.x * 256 + threadIdx.x;      // < 36*2048 = 73728
  int tk = e >> 11;
  int r  = e & 2047;
  int ocl = r >> 6, kl = r & 63;
  int k = tk * 64 + kl;
  int kk = k >> 8, c = k & 255;
  float v = (ocl < 27) ? woff[((size_t)(ocl * 256 + c)) * 9 + kk] : 0.f;
  Wot[e] = __float2bfloat16(v);
}

// ---------------------------------------------------------------------------
// KT: transpose x (B,C,H,W) f32 -> xT[b][hw][c] f32
// ---------------------------------------------------------------------------
__global__ __launch_bounds__(256) void kt_xt(const float* __restrict__ x,
                                             float* __restrict__ xT) {
  __shared__ float t[64][65];
  int blk = blockIdx.x;
  int hwg = blk & 63;
  int cg  = (blk >> 6) & 3;
  int b   = blk >> 8;
  int hw0 = hwg * 64, c0 = cg * 64;
  int l = threadIdx.x & 63, q = threadIdx.x >> 6;
  const float* xb = x + ((size_t)(b * 256 + c0) << 12) + hw0;
#pragma unroll
  for (int i = 0; i < 16; ++i) {
    int cl = q * 16 + i;
    t[cl][l] = xb[((size_t)cl << 12) + l];
  }
  __syncthreads();
  float* xTb = xT + (((size_t)b << 12) + hw0) * 256 + c0;
#pragma unroll
  for (int i = 0; i < 16; ++i) {
    int hwl = q * 16 + i;
    xTb[(size_t)hwl * 256 + l] = t[l][hwl];
  }
}

// ---------------------------------------------------------------------------
// K1: offset conv as MFMA GEMM (64 m x 32 oc per block, grid 256, XCD-swz).
// ---------------------------------------------------------------------------
__global__ __launch_bounds__(256) void k1_omgemm(const float* __restrict__ xT,
                                                 const __hip_bfloat16* __restrict__ Wot,
                                                 const float* __restrict__ boff,
                                                 float* __restrict__ om) {
  __shared__ __align__(16) __hip_bfloat16 sP[64 * 64];
  __shared__ __align__(16) __hip_bfloat16 sWo[32 * 64];
  int bid = blockIdx.x;
  int tm = ((bid & 7) << 5) | (bid >> 3);   // chunked XCD swizzle (256%8==0)
  int tid = threadIdx.x;
  int wv = tid >> 6, lane = tid & 63;
  int lo = lane & 15, hi = lane >> 4;

  int r0 = tid >> 3;            // 0..31
  int kb = (tid & 7) * 8;       // 0..56

  f32x4 zero4 = {0.f, 0.f, 0.f, 0.f};
  f32x4 acc[2] = {zero4, zero4};

  for (int tk = 0; tk < NKSTEP; ++tk) {
    async16((const char*)Wot + (size_t)tk * 4096 + tid * 16, (char*)sWo + tid * 16);

    int kk = tk >> 2, cc = tk & 3;
    int ky = kk / 3, kx = kk - ky * 3;
#pragma unroll
    for (int half = 0; half < 2; ++half) {
      int row = r0 + half * 32;
      int m_s = tm * 64 + row;
      int b_s = m_s >> 12, hw_s = m_s & 4095, h_s = hw_s >> 6, w_s = hw_s & 63;
      int yy = h_s + ky - 1, xx = w_s + kx - 1;
      bool valid = ((unsigned)yy < 64u) && ((unsigned)xx < 64u);
      short8 h8 = {0, 0, 0, 0, 0, 0, 0, 0};
      if (valid) {
        const float* src = xT + ((((size_t)b_s << 12) + yy * 64 + xx) << 8) + cc * 64 + kb;
        f32x4 u0 = *(const f32x4*)src;
        f32x4 u1 = *(const f32x4*)(src + 4);
        __hip_bfloat16 tmp[8];
#pragma unroll
        for (int j = 0; j < 4; ++j) {
          tmp[j]     = __float2bfloat16(u0[j]);
          tmp[4 + j] = __float2bfloat16(u1[j]);
        }
        h8 = *(const short8*)tmp;
      }
      *(short8*)&sP[row * 64 + kb] = h8;
    }
    __syncthreads();

    short8 bfr[2], a[2][2];
#pragma unroll
    for (int kc = 0; kc < 2; ++kc) {
      bfr[kc] = *(const short8*)&sP[(wv * 16 + lo) * 64 + kc * 32 + hi * 8];
#pragma unroll
      for (int f = 0; f < 2; ++f)
        a[f][kc] = *(const short8*)&sWo[(f * 16 + lo) * 64 + kc * 32 + hi * 8];
    }
#pragma unroll
    for (int f = 0; f < 2; ++f)
#pragma unroll
      for (int kc = 0; kc < 2; ++kc)
        acc[f] = __builtin_amdgcn_mfma_f32_16x16x32_bf16(a[f][kc], bfr[kc], acc[f], 0, 0, 0);
    __syncthreads();
  }

  int m_o = tm * 64 + wv * 16 + lo;
  int b_o = m_o >> 12, hw_o = m_o & 4095;
#pragma unroll
  for (int f = 0; f < 2; ++f) {
#pragma unroll
    for (int r = 0; r < 4; ++r) {
      int oc = f * 16 + hi * 4 + r;
      if (oc < 27)
        om[(((size_t)(b_o * 27 + oc)) << 12) + hw_o] = acc[f][r] + boff[oc];
    }
  }
}

// ---------------------------------------------------------------------------
// K23: fused deformable-gather + GEMM. 64 m x 256 o per block, grid 256.
// Chunked XCD swizzle -> per-XCD xT working set ~2.2MB (fits 4MB L2).
// sW: XOR-swizzled source (k0) + linear global_load_lds + XOR ds_read.
// sV: XOR-swizzled write + XOR ds_read (both in-kernel). 16-way -> 2-way.
// ---------------------------------------------------------------------------
__global__ __launch_bounds__(256) void k23_fused(const float* __restrict__ xT,
                                                 const float* __restrict__ om,
                                                 const __hip_bfloat16* __restrict__ Wt2,
                                                 float* __restrict__ out) {
  __shared__ __align__(16) __hip_bfloat16 sW[256 * 64];   // 32 KB
  __shared__ __align__(16) __hip_bfloat16 sV[64 * 64];    // 8 KB
  __shared__ float sw00[576], sw01[576], sw10[576], sw11[576];
  __shared__ int   so00[576], so01[576], so10[576], so11[576];

  int bid = blockIdx.x;
  int tm = ((bid & 7) << 5) | (bid >> 3);   // chunked XCD swizzle
  int tid = threadIdx.x;
  int wv = tid >> 6, lane = tid & 63;
  int lo = lane & 15, hi = lane >> 4;
  int b = tm >> 6;
  int m0 = tm * 64;

  // ---- prologue: gather params for (row 0..63) x (kk 0..8) ----
  for (int it = tid; it < 576; it += 256) {
    int kk = it >> 6, row = it & 63;
    int m = m0 + row;
    int hw = m & 4095, h = hw >> 6, w = hw & 63;
    const float* omb = om + ((size_t)(b * 27) << 12) + hw;
    float dy = omb[(size_t)(2 * kk) << 12];
    float dx = omb[(size_t)(2 * kk + 1) << 12];
    float mz = omb[(size_t)(18 + kk) << 12];
    int ky = kk / 3, kx = kk - ky * 3;
    float py = dy + (float)(h - 1 + ky);
    float px = dx + (float)(w - 1 + kx);
    float y0f = floorf(py), x0f = floorf(px);
    float wy = py - y0f, wx = px - x0f;
    int y0 = (int)y0f, x0 = (int)x0f;
    bool vy0 = (unsigned)y0 < 64u, vy1 = (unsigned)(y0 + 1) < 64u;
    bool vx0 = (unsigned)x0 < 64u, vx1 = (unsigned)(x0 + 1) < 64u;
    int cy0 = min(max(y0, 0), 63), cy1 = min(max(y0 + 1, 0), 63);
    int cx0 = min(max(x0, 0), 63), cx1 = min(max(x0 + 1, 0), 63);
    float mask = 1.f / (1.f + __expf(-mz));
    sw00[it] = (vy0 && vx0) ? (1.f - wy) * (1.f - wx) * mask : 0.f;
    sw01[it] = (vy0 && vx1) ? (1.f - wy) * wx * mask : 0.f;
    sw10[it] = (vy1 && vx0) ? wy * (1.f - wx) * mask : 0.f;
    sw11[it] = (vy1 && vx1) ? wy * wx * mask : 0.f;
    so00[it] = cy0 * 64 + cx0;
    so01[it] = cy0 * 64 + cx1;
    so10[it] = cy1 * 64 + cx0;
    so11[it] = cy1 * 64 + cx1;
  }
  __syncthreads();

  f32x4 zero4 = {0.f, 0.f, 0.f, 0.f};
  f32x4 acc[4][4];              // [fo][fm]
#pragma unroll
  for (int fo = 0; fo < 4; ++fo)
#pragma unroll
    for (int fm = 0; fm < 4; ++fm) acc[fo][fm] = zero4;

  const float* xb = xT + (((size_t)b << 12) << 8);
  int vrow0 = tid >> 3;         // 0..31 (8 threads/row, 8 ch each)
  int chq   = tid & 7;          // channel-octet within 64-k tile

  for (int tk = 0; tk < NKSTEP; ++tk) {
    // stage W tile [256o][64k] = 32KB (source pre-swizzled; LDS linear)
#pragma unroll
    for (int j = 0; j < 8; ++j) {
      int off = (j * 256 + tid) * 16;
      async16((const char*)Wt2 + (size_t)tk * 32768 + off, (char*)sW + off);
    }
    int kk = tk >> 2, cc = tk & 3;
    // build V tile [64m][64k]: 2 passes of 32 rows, ds_write_b128
#pragma unroll
    for (int p = 0; p < 2; ++p) {
      int row = vrow0 + p * 32;
      int it = kk * 64 + row;
      const float* base = xb + cc * 64 + chq * 8;
      const float* p00 = base + ((size_t)so00[it] << 8);
      const float* p01 = base + ((size_t)so01[it] << 8);
      const float* p10 = base + ((size_t)so10[it] << 8);
      const float* p11 = base + ((size_t)so11[it] << 8);
      f32x4 t00a = *(const f32x4*)p00, t00b = *(const f32x4*)(p00 + 4);
      f32x4 t01a = *(const f32x4*)p01, t01b = *(const f32x4*)(p01 + 4);
      f32x4 t10a = *(const f32x4*)p10, t10b = *(const f32x4*)(p10 + 4);
      f32x4 t11a = *(const f32x4*)p11, t11b = *(const f32x4*)(p11 + 4);
      float a00 = sw00[it], a01 = sw01[it], a10 = sw10[it], a11 = sw11[it];
      __hip_bfloat16 h8[8];
#pragma unroll
      for (int j = 0; j < 4; ++j) {
        float v0 = a00 * t00a[j] + a01 * t01a[j] + a10 * t10a[j] + a11 * t11a[j];
        float v1 = a00 * t00b[j] + a01 * t01b[j] + a10 * t10b[j] + a11 * t11b[j];
        h8[j]     = __float2bfloat16(v0);
        h8[4 + j] = __float2bfloat16(v1);
      }
      int colz = (chq * 8) ^ ((row & 7) << 3);
      *(short8*)&sV[row * 64 + colz] = *(const short8*)h8;
    }
    __syncthreads();

    short8 bfr[4][2];
#pragma unroll
    for (int fm = 0; fm < 4; ++fm)
#pragma unroll
      for (int kc = 0; kc < 2; ++kc)
        bfr[fm][kc] = *(const short8*)&sV[(fm * 16 + lo) * 64
                                         + ((kc * 32 + hi * 8) ^ ((lo & 7) << 3))];

#pragma unroll
    for (int fo = 0; fo < 4; ++fo) {
      int rw = wv * 64 + fo * 16 + lo;
      short8 a0 = *(const short8*)&sW[rw * 64 + ((hi * 8) ^ ((lo & 7) << 3))];
      short8 a1 = *(const short8*)&sW[rw * 64 + ((32 + hi * 8) ^ ((lo & 7) << 3))];
#pragma unroll
      for (int fm = 0; fm < 4; ++fm) {
        acc[fo][fm] = __builtin_amdgcn_mfma_f32_16x16x32_bf16(a0, bfr[fm][0], acc[fo][fm], 0, 0, 0);
        acc[fo][fm] = __builtin_amdgcn_mfma_f32_16x16x32_bf16(a1, bfr[fm][1], acc[fo][fm], 0, 0, 0);
      }
    }
    __syncthreads();
  }

  // epilogue: C layout col = lane&15 -> m, row = hi*4+r -> o
  int hwbase = m0 & 4095;
#pragma unroll
  for (int fo = 0; fo < 4; ++fo) {
    int o = wv * 64 + fo * 16 + hi * 4;
#pragma unroll
    for (int fm = 0; fm < 4; ++fm) {
      int mloc = hwbase + fm * 16 + lo;
#pragma unroll
      for (int r = 0; r < 4; ++r)
        out[((size_t)(b * 256 + o + r)) * 4096 + mloc] = acc[fo][fm][r];
    }
  }
}

// ---------------------------------------------------------------------------
extern "C" void kernel_launch(void* const* d_in, const int* in_sizes, int n_in,
                              void* d_out, int out_size, void* d_ws, size_t ws_size,
                              hipStream_t stream) {
  (void)in_sizes; (void)n_in; (void)out_size; (void)ws_size;
  const float* x     = (const float*)d_in[0];
  const float* woff  = (const float*)d_in[1];
  const float* boff  = (const float*)d_in[2];
  const float* wconv = (const float*)d_in[3];
  char* ws = (char*)d_ws;
  float* om   = (float*)(ws + OM_OFF);
  float* xT   = (float*)(ws + XT_OFF);
  __hip_bfloat16* Wt2 = (__hip_bfloat16*)(ws + WT_OFF);
  __hip_bfloat16* Wot = (__hip_bfloat16*)(ws + WOT_OFF);
  float* out = (float*)d_out;

  hipLaunchKernelGGL(k0_wt,     dim3(2304), dim3(256), 0, stream, wconv, Wt2);
  hipLaunchKernelGGL(k0b_wot,   dim3(288),  dim3(256), 0, stream, woff, Wot);
  hipLaunchKernelGGL(kt_xt,     dim3(1024), dim3(256), 0, stream, x, xT);
  hipLaunchKernelGGL(k1_omgemm, dim3(256),  dim3(256), 0, stream, xT, Wot, boff, om);
  hipLaunchKernelGGL(k23_fused, dim3(256),  dim3(256), 0, stream, xT, om, Wt2, out);
}

// Round 8
// 107.069 us; speedup vs baseline: 1.2567x; 1.1149x over previous
//
#include <hip/hip_runtime.h>
#include <hip/hip_bf16.h>

// Problem constants
#define XH   64
#define XW   64
#define CIN  256
#define COUT 256
#define BATCH 4
#define KK9  9
#define M_TOT 16384      // BATCH*XH*XW
#define K_TOT 2304       // KK9*CIN
#define NKSTEP 36        // K_TOT/64

typedef __attribute__((ext_vector_type(8))) short short8;
typedef __attribute__((ext_vector_type(4))) short short4v;
typedef __attribute__((ext_vector_type(4))) float f32x4;

// Workspace layout (bytes)
#define OM_OFF   0
#define OM_BYTES (BATCH*27*4096*4)            // 1,769,472
#define XT_OFF   (OM_OFF + OM_BYTES)
#define XT_BYTES (BATCH*4096*CIN*4)           // 16,777,216
#define WT_OFF   (XT_OFF + XT_BYTES)
#define WT_BYTES (COUT*K_TOT*2)               // 1,179,648  ([tk][256o][64k], XOR-swizzled)
#define WOT_OFF  (WT_OFF + WT_BYTES)
#define WOT_BYTES (36*32*64*2)                // 147,456

__device__ __forceinline__ void async16(const void* g, void* l) {
  __builtin_amdgcn_global_load_lds((const __attribute__((address_space(1))) void*)g,
                                   (__attribute__((address_space(3))) void*)l,
                                   16, 0, 0);
}

// ---------------------------------------------------------------------------
// K0: w_conv (O,C,3,3) f32 -> Wt2 tiled bf16: [tk(36)][256 o][64 j],
// j = k_local ^ ((o&7)<<3)  (pre-swizzled source; LDS staged linearly)
// ---------------------------------------------------------------------------
__global__ __launch_bounds__(256) void k0_wt(const float* __restrict__ wconv,
                                             __hip_bfloat16* __restrict__ Wt2) {
  int e = blockIdx.x * 256 + threadIdx.x;      // < 36*16384 = 589824
  int tk = e >> 14;
  int r  = e & 16383;
  int o  = r >> 6, j = r & 63;
  int kl = j ^ ((o & 7) << 3);
  int k  = tk * 64 + kl;
  int kk = k >> 8, c = k & 255;
  float v = wconv[(o * CIN + c) * KK9 + kk];
  Wt2[e] = __float2bfloat16(v);
}

// ---------------------------------------------------------------------------
// K0b: w_off (27,C,3,3) f32 -> Wot tiled bf16: [tk(36)][32 oc][64 k]
// ---------------------------------------------------------------------------
__global__ __launch_bounds__(256) void k0b_wot(const float* __restrict__ woff,
                                               __hip_bfloat16* __restrict__ Wot) {
  int e = blockIdx.x * 256 + threadIdx.x;      // < 36*2048 = 73728
  int tk = e >> 11;
  int r  = e & 2047;
  int ocl = r >> 6, kl = r & 63;
  int k = tk * 64 + kl;
  int kk = k >> 8, c = k & 255;
  float v = (ocl < 27) ? woff[((size_t)(ocl * 256 + c)) * 9 + kk] : 0.f;
  Wot[e] = __float2bfloat16(v);
}

// ---------------------------------------------------------------------------
// KT: transpose x (B,C,H,W) f32 -> xT[b][hw][c] f32
// ---------------------------------------------------------------------------
__global__ __launch_bounds__(256) void kt_xt(const float* __restrict__ x,
                                             float* __restrict__ xT) {
  __shared__ float t[64][65];
  int blk = blockIdx.x;
  int hwg = blk & 63;
  int cg  = (blk >> 6) & 3;
  int b   = blk >> 8;
  int hw0 = hwg * 64, c0 = cg * 64;
  int l = threadIdx.x & 63, q = threadIdx.x >> 6;
  const float* xb = x + ((size_t)(b * 256 + c0) << 12) + hw0;
#pragma unroll
  for (int i = 0; i < 16; ++i) {
    int cl = q * 16 + i;
    t[cl][l] = xb[((size_t)cl << 12) + l];
  }
  __syncthreads();
  float* xTb = xT + (((size_t)b << 12) + hw0) * 256 + c0;
#pragma unroll
  for (int i = 0; i < 16; ++i) {
    int hwl = q * 16 + i;
    xTb[(size_t)hwl * 256 + l] = t[l][hwl];
  }
}

// ---------------------------------------------------------------------------
// K1: offset conv as MFMA GEMM (64 m x 32 oc per block, grid 256, XCD-swz).
// ---------------------------------------------------------------------------
__global__ __launch_bounds__(256) void k1_omgemm(const float* __restrict__ xT,
                                                 const __hip_bfloat16* __restrict__ Wot,
                                                 const float* __restrict__ boff,
                                                 float* __restrict__ om) {
  __shared__ __align__(16) __hip_bfloat16 sP[64 * 64];
  __shared__ __align__(16) __hip_bfloat16 sWo[32 * 64];
  int bid = blockIdx.x;
  int tm = ((bid & 7) << 5) | (bid >> 3);   // chunked XCD swizzle
  int tid = threadIdx.x;
  int wv = tid >> 6, lane = tid & 63;
  int lo = lane & 15, hi = lane >> 4;

  int r0 = tid >> 3;
  int kb = (tid & 7) * 8;

  f32x4 zero4 = {0.f, 0.f, 0.f, 0.f};
  f32x4 acc[2] = {zero4, zero4};

  for (int tk = 0; tk < NKSTEP; ++tk) {
    async16((const char*)Wot + (size_t)tk * 4096 + tid * 16, (char*)sWo + tid * 16);

    int kk = tk >> 2, cc = tk & 3;
    int ky = kk / 3, kx = kk - ky * 3;
#pragma unroll
    for (int half = 0; half < 2; ++half) {
      int row = r0 + half * 32;
      int m_s = tm * 64 + row;
      int b_s = m_s >> 12, hw_s = m_s & 4095, h_s = hw_s >> 6, w_s = hw_s & 63;
      int yy = h_s + ky - 1, xx = w_s + kx - 1;
      bool valid = ((unsigned)yy < 64u) && ((unsigned)xx < 64u);
      short8 h8 = {0, 0, 0, 0, 0, 0, 0, 0};
      if (valid) {
        const float* src = xT + ((((size_t)b_s << 12) + yy * 64 + xx) << 8) + cc * 64 + kb;
        f32x4 u0 = *(const f32x4*)src;
        f32x4 u1 = *(const f32x4*)(src + 4);
        __hip_bfloat16 tmp[8];
#pragma unroll
        for (int j = 0; j < 4; ++j) {
          tmp[j]     = __float2bfloat16(u0[j]);
          tmp[4 + j] = __float2bfloat16(u1[j]);
        }
        h8 = *(const short8*)tmp;
      }
      *(short8*)&sP[row * 64 + kb] = h8;
    }
    __syncthreads();

    short8 bfr[2], a[2][2];
#pragma unroll
    for (int kc = 0; kc < 2; ++kc) {
      bfr[kc] = *(const short8*)&sP[(wv * 16 + lo) * 64 + kc * 32 + hi * 8];
#pragma unroll
      for (int f = 0; f < 2; ++f)
        a[f][kc] = *(const short8*)&sWo[(f * 16 + lo) * 64 + kc * 32 + hi * 8];
    }
#pragma unroll
    for (int f = 0; f < 2; ++f)
#pragma unroll
      for (int kc = 0; kc < 2; ++kc)
        acc[f] = __builtin_amdgcn_mfma_f32_16x16x32_bf16(a[f][kc], bfr[kc], acc[f], 0, 0, 0);
    __syncthreads();
  }

  int m_o = tm * 64 + wv * 16 + lo;
  int b_o = m_o >> 12, hw_o = m_o & 4095;
#pragma unroll
  for (int f = 0; f < 2; ++f) {
#pragma unroll
    for (int r = 0; r < 4; ++r) {
      int oc = f * 16 + hi * 4 + r;
      if (oc < 27)
        om[(((size_t)(b_o * 27 + oc)) << 12) + hw_o] = acc[f][r] + boff[oc];
    }
  }
}

// ---------------------------------------------------------------------------
// K23: fused deformable-gather + GEMM. 64 m x 256 o per block, grid 256,
// 512 threads (8 waves; wave wv owns o in [wv*32, wv*32+32)).
// 2-deep pipeline: double-buffered sW (async16) + sV (reg-staged taps),
// ONE barrier per K-step. XCD-chunked block swizzle. XOR-swizzled LDS.
// ---------------------------------------------------------------------------
__global__ __launch_bounds__(512) void k23_fused(const float* __restrict__ xT,
                                                 const float* __restrict__ om,
                                                 const __hip_bfloat16* __restrict__ Wt2,
                                                 float* __restrict__ out) {
  __shared__ __align__(16) __hip_bfloat16 sW[2][256 * 64];   // 64 KB
  __shared__ __align__(16) __hip_bfloat16 sV[2][64 * 64];    // 16 KB
  __shared__ float sw00[576], sw01[576], sw10[576], sw11[576];
  __shared__ int   so00[576], so01[576], so10[576], so11[576];

  int bid = blockIdx.x;
  int tm = ((bid & 7) << 5) | (bid >> 3);   // chunked XCD swizzle
  int tid = threadIdx.x;
  int wv = tid >> 6, lane = tid & 63;
  int lo = lane & 15, hi = lane >> 4;
  int b = tm >> 6;
  int m0 = tm * 64;

  // ---- prologue A: gather params for (kk 0..8) x (row 0..63) ----
  for (int it = tid; it < 576; it += 512) {
    int kk = it >> 6, row = it & 63;
    int m = m0 + row;
    int hw = m & 4095, h = hw >> 6, w = hw & 63;
    const float* omb = om + ((size_t)(b * 27) << 12) + hw;
    float dy = omb[(size_t)(2 * kk) << 12];
    float dx = omb[(size_t)(2 * kk + 1) << 12];
    float mz = omb[(size_t)(18 + kk) << 12];
    int ky = kk / 3, kx = kk - ky * 3;
    float py = dy + (float)(h - 1 + ky);
    float px = dx + (float)(w - 1 + kx);
    float y0f = floorf(py), x0f = floorf(px);
    float wy = py - y0f, wx = px - x0f;
    int y0 = (int)y0f, x0 = (int)x0f;
    bool vy0 = (unsigned)y0 < 64u, vy1 = (unsigned)(y0 + 1) < 64u;
    bool vx0 = (unsigned)x0 < 64u, vx1 = (unsigned)(x0 + 1) < 64u;
    int cy0 = min(max(y0, 0), 63), cy1 = min(max(y0 + 1, 0), 63);
    int cx0 = min(max(x0, 0), 63), cx1 = min(max(x0 + 1, 0), 63);
    float mask = 1.f / (1.f + __expf(-mz));
    sw00[it] = (vy0 && vx0) ? (1.f - wy) * (1.f - wx) * mask : 0.f;
    sw01[it] = (vy0 && vx1) ? (1.f - wy) * wx * mask : 0.f;
    sw10[it] = (vy1 && vx0) ? wy * (1.f - wx) * mask : 0.f;
    sw11[it] = (vy1 && vx1) ? wy * wx * mask : 0.f;
    so00[it] = cy0 * 64 + cx0;
    so01[it] = cy0 * 64 + cx1;
    so10[it] = cy1 * 64 + cx0;
    so11[it] = cy1 * 64 + cx1;
  }
  __syncthreads();   // params visible to all (needed for tk=0 build below)

  const float* xb = xT + (((size_t)b << 12) << 8);
  int vrow = tid >> 3;          // 0..63 (8 threads/row, 8 ch each)
  int chq  = tid & 7;

  // ---- prologue B: stage W(0) and build V(0) into buffer 0 ----
#pragma unroll
  for (int j = 0; j < 4; ++j) {
    int off = (j * 512 + tid) * 16;
    async16((const char*)Wt2 + off, (char*)sW[0] + off);
  }
  {
    int it = vrow;  // kk=0
    const float* base = xb + chq * 8;   // cc=0
    const float* p00 = base + ((size_t)so00[it] << 8);
    const float* p01 = base + ((size_t)so01[it] << 8);
    const float* p10 = base + ((size_t)so10[it] << 8);
    const float* p11 = base + ((size_t)so11[it] << 8);
    f32x4 t00a = *(const f32x4*)p00, t00b = *(const f32x4*)(p00 + 4);
    f32x4 t01a = *(const f32x4*)p01, t01b = *(const f32x4*)(p01 + 4);
    f32x4 t10a = *(const f32x4*)p10, t10b = *(const f32x4*)(p10 + 4);
    f32x4 t11a = *(const f32x4*)p11, t11b = *(const f32x4*)(p11 + 4);
    float a00 = sw00[it], a01 = sw01[it], a10 = sw10[it], a11 = sw11[it];
    __hip_bfloat16 h8[8];
#pragma unroll
    for (int j = 0; j < 4; ++j) {
      float v0 = a00 * t00a[j] + a01 * t01a[j] + a10 * t10a[j] + a11 * t11a[j];
      float v1 = a00 * t00b[j] + a01 * t01b[j] + a10 * t10b[j] + a11 * t11b[j];
      h8[j]     = __float2bfloat16(v0);
      h8[4 + j] = __float2bfloat16(v1);
    }
    int colz = (chq * 8) ^ ((vrow & 7) << 3);
    *(short8*)&sV[0][vrow * 64 + colz] = *(const short8*)h8;
  }
  __syncthreads();   // buffer 0 ready (implicit vmcnt drain covers async16)

  f32x4 zero4 = {0.f, 0.f, 0.f, 0.f};
  f32x4 acc[2][4];              // [fo][fm]
#pragma unroll
  for (int fo = 0; fo < 2; ++fo)
#pragma unroll
    for (int fm = 0; fm < 4; ++fm) acc[fo][fm] = zero4;

  for (int tk = 0; tk < NKSTEP; ++tk) {
    int cb = tk & 1, nb = cb ^ 1;
    bool more = (tk < NKSTEP - 1);

    // (1) issue W prefetch for tk+1 into sW[nb]
    if (more) {
#pragma unroll
      for (int j = 0; j < 4; ++j) {
        int off = (j * 512 + tid) * 16;
        async16((const char*)Wt2 + (size_t)(tk + 1) * 32768 + off, (char*)sW[nb] + off);
      }
    }
    // (2) issue tap loads for tk+1 into registers
    f32x4 t00a, t00b, t01a, t01b, t10a, t10b, t11a, t11b;
    int itn = 0;
    if (more) {
      int tkn = tk + 1;
      int kkn = tkn >> 2, ccn = tkn & 3;
      itn = kkn * 64 + vrow;
      const float* base = xb + ccn * 64 + chq * 8;
      const float* p00 = base + ((size_t)so00[itn] << 8);
      const float* p01 = base + ((size_t)so01[itn] << 8);
      const float* p10 = base + ((size_t)so10[itn] << 8);
      const float* p11 = base + ((size_t)so11[itn] << 8);
      t00a = *(const f32x4*)p00; t00b = *(const f32x4*)(p00 + 4);
      t01a = *(const f32x4*)p01; t01b = *(const f32x4*)(p01 + 4);
      t10a = *(const f32x4*)p10; t10b = *(const f32x4*)(p10 + 4);
      t11a = *(const f32x4*)p11; t11b = *(const f32x4*)(p11 + 4);
    }

    // (3) MFMA on current buffers
    short8 bfr[4][2];
#pragma unroll
    for (int fm = 0; fm < 4; ++fm)
#pragma unroll
      for (int kc = 0; kc < 2; ++kc)
        bfr[fm][kc] = *(const short8*)&sV[cb][(fm * 16 + lo) * 64
                                             + ((kc * 32 + hi * 8) ^ ((lo & 7) << 3))];
#pragma unroll
    for (int fo = 0; fo < 2; ++fo) {
      int rw = wv * 32 + fo * 16 + lo;
      short8 a0 = *(const short8*)&sW[cb][rw * 64 + ((hi * 8) ^ ((lo & 7) << 3))];
      short8 a1 = *(const short8*)&sW[cb][rw * 64 + ((32 + hi * 8) ^ ((lo & 7) << 3))];
#pragma unroll
      for (int fm = 0; fm < 4; ++fm) {
        acc[fo][fm] = __builtin_amdgcn_mfma_f32_16x16x32_bf16(a0, bfr[fm][0], acc[fo][fm], 0, 0, 0);
        acc[fo][fm] = __builtin_amdgcn_mfma_f32_16x16x32_bf16(a1, bfr[fm][1], acc[fo][fm], 0, 0, 0);
      }
    }

    // (4) convert taps -> sV[nb]
    if (more) {
      float a00 = sw00[itn], a01 = sw01[itn], a10 = sw10[itn], a11 = sw11[itn];
      __hip_bfloat16 h8[8];
#pragma unroll
      for (int j = 0; j < 4; ++j) {
        float v0 = a00 * t00a[j] + a01 * t01a[j] + a10 * t10a[j] + a11 * t11a[j];
        float v1 = a00 * t00b[j] + a01 * t01b[j] + a10 * t10b[j] + a11 * t11b[j];
        h8[j]     = __float2bfloat16(v0);
        h8[4 + j] = __float2bfloat16(v1);
      }
      int colz = (chq * 8) ^ ((vrow & 7) << 3);
      *(short8*)&sV[nb][vrow * 64 + colz] = *(const short8*)h8;
    }
    __syncthreads();   // next buffers ready; drains async16 + tap loads
  }

  // epilogue: C layout col = lane&15 -> m, row = hi*4+r -> o
  int hwbase = m0 & 4095;
#pragma unroll
  for (int fo = 0; fo < 2; ++fo) {
    int o = wv * 32 + fo * 16 + hi * 4;
#pragma unroll
    for (int fm = 0; fm < 4; ++fm) {
      int mloc = hwbase + fm * 16 + lo;
#pragma unroll
      for (int r = 0; r < 4; ++r)
        out[((size_t)(b * 256 + o + r)) * 4096 + mloc] = acc[fo][fm][r];
    }
  }
}

// ---------------------------------------------------------------------------
extern "C" void kernel_launch(void* const* d_in, const int* in_sizes, int n_in,
                              void* d_out, int out_size, void* d_ws, size_t ws_size,
                              hipStream_t stream) {
  (void)in_sizes; (void)n_in; (void)out_size; (void)ws_size;
  const float* x     = (const float*)d_in[0];
  const float* woff  = (const float*)d_in[1];
  const float* boff  = (const float*)d_in[2];
  const float* wconv = (const float*)d_in[3];
  char* ws = (char*)d_ws;
  float* om   = (float*)(ws + OM_OFF);
  float* xT   = (float*)(ws + XT_OFF);
  __hip_bfloat16* Wt2 = (__hip_bfloat16*)(ws + WT_OFF);
  __hip_bfloat16* Wot = (__hip_bfloat16*)(ws + WOT_OFF);
  float* out = (float*)d_out;

  hipLaunchKernelGGL(k0_wt,     dim3(2304), dim3(256), 0, stream, wconv, Wt2);
  hipLaunchKernelGGL(k0b_wot,   dim3(288),  dim3(256), 0, stream, woff, Wot);
  hipLaunchKernelGGL(kt_xt,     dim3(1024), dim3(256), 0, stream, x, xT);
  hipLaunchKernelGGL(k1_omgemm, dim3(256),  dim3(256), 0, stream, xT, Wot, boff, om);
  hipLaunchKernelGGL(k23_fused, dim3(256),  dim3(512), 0, stream, xT, om, Wt2, out);
}

// Round 9
// 90.318 us; speedup vs baseline: 1.4898x; 1.1855x over previous
//
#include <hip/hip_runtime.h>
#include <hip/hip_bf16.h>

// Problem constants
#define XH   64
#define XW   64
#define CIN  256
#define COUT 256
#define BATCH 4
#define KK9  9
#define M_TOT 16384      // BATCH*XH*XW
#define K_TOT 2304       // KK9*CIN
#define NKSTEP 36        // K_TOT/64

typedef __attribute__((ext_vector_type(8))) short short8;
typedef __attribute__((ext_vector_type(4))) float f32x4;

// Workspace layout (bytes)
#define OM_OFF   0
#define OM_BYTES (BATCH*27*4096*4)            // 1,769,472
#define XT_OFF   (OM_OFF + OM_BYTES)
#define XT_BYTES (BATCH*4096*CIN*2)           // 8,388,608 (bf16 now)
#define WT_OFF   (XT_OFF + XT_BYTES)
#define WT_BYTES (COUT*K_TOT*2)               // 1,179,648  ([tk][256o][64j], XOR-pre-swizzled)
#define WOT_OFF  (WT_OFF + WT_BYTES)
#define WOT_BYTES (36*32*64*2)                // 147,456

__device__ __forceinline__ void async16(const void* g, void* l) {
  __builtin_amdgcn_global_load_lds((const __attribute__((address_space(1))) void*)g,
                                   (__attribute__((address_space(3))) void*)l,
                                   16, 0, 0);
}

__device__ __forceinline__ float b2f(short s) {
  union { float f; unsigned u; } x;
  x.u = ((unsigned)(unsigned short)s) << 16;
  return x.f;
}

// ---------------------------------------------------------------------------
// K0: w_conv (O,C,3,3) f32 -> Wt2 tiled bf16: [tk(36)][256 o][64 j],
// j = k_local ^ ((o&7)<<3)  (pre-swizzled source; LDS copy stays linear)
// ---------------------------------------------------------------------------
__global__ __launch_bounds__(256) void k0_wt(const float* __restrict__ wconv,
                                             __hip_bfloat16* __restrict__ Wt2) {
  int e = blockIdx.x * 256 + threadIdx.x;      // < 36*16384 = 589824
  int tk = e >> 14;
  int r  = e & 16383;
  int o  = r >> 6, j = r & 63;
  int kl = j ^ ((o & 7) << 3);
  int k  = tk * 64 + kl;
  int kk = k >> 8, c = k & 255;
  float v = wconv[(o * CIN + c) * KK9 + kk];
  Wt2[e] = __float2bfloat16(v);
}

// ---------------------------------------------------------------------------
// K0b: w_off (27,C,3,3) f32 -> Wot tiled bf16: [tk(36)][32 oc][64 k]
// ---------------------------------------------------------------------------
__global__ __launch_bounds__(256) void k0b_wot(const float* __restrict__ woff,
                                               __hip_bfloat16* __restrict__ Wot) {
  int e = blockIdx.x * 256 + threadIdx.x;      // < 36*2048 = 73728
  int tk = e >> 11;
  int r  = e & 2047;
  int ocl = r >> 6, kl = r & 63;
  int k = tk * 64 + kl;
  int kk = k >> 8, c = k & 255;
  float v = (ocl < 27) ? woff[((size_t)(ocl * 256 + c)) * 9 + kk] : 0.f;
  Wot[e] = __float2bfloat16(v);
}

// ---------------------------------------------------------------------------
// KT: transpose x (B,C,H,W) f32 -> xTh[b][hw][c] bf16 (channel-contiguous)
// ---------------------------------------------------------------------------
__global__ __launch_bounds__(256) void kt_xt(const float* __restrict__ x,
                                             __hip_bfloat16* __restrict__ xTh) {
  __shared__ float t[64][65];
  int blk = blockIdx.x;
  int hwg = blk & 63;
  int cg  = (blk >> 6) & 3;
  int b   = blk >> 8;
  int hw0 = hwg * 64, c0 = cg * 64;
  int l = threadIdx.x & 63, q = threadIdx.x >> 6;
  const float* xb = x + ((size_t)(b * 256 + c0) << 12) + hw0;
#pragma unroll
  for (int i = 0; i < 16; ++i) {
    int cl = q * 16 + i;
    t[cl][l] = xb[((size_t)cl << 12) + l];
  }
  __syncthreads();
  __hip_bfloat16* xTb = xTh + (((size_t)b << 12) + hw0) * 256 + c0;
#pragma unroll
  for (int i = 0; i < 16; ++i) {
    int hwl = q * 16 + i;
    xTb[(size_t)hwl * 256 + l] = __float2bfloat16(t[l][hwl]);
  }
}

// ---------------------------------------------------------------------------
// K1: offset conv as MFMA GEMM (64 m x 32 oc per block, grid 256, XCD-swz).
// Reads bf16 xTh directly (no conversion needed in staging).
// ---------------------------------------------------------------------------
__global__ __launch_bounds__(256) void k1_omgemm(const __hip_bfloat16* __restrict__ xTh,
                                                 const __hip_bfloat16* __restrict__ Wot,
                                                 const float* __restrict__ boff,
                                                 float* __restrict__ om) {
  __shared__ __align__(16) __hip_bfloat16 sP[64 * 64];
  __shared__ __align__(16) __hip_bfloat16 sWo[32 * 64];
  int bid = blockIdx.x;
  int tm = ((bid & 7) << 5) | (bid >> 3);   // chunked XCD swizzle
  int tid = threadIdx.x;
  int wv = tid >> 6, lane = tid & 63;
  int lo = lane & 15, hi = lane >> 4;

  int r0 = tid >> 3;
  int kb = (tid & 7) * 8;

  f32x4 zero4 = {0.f, 0.f, 0.f, 0.f};
  f32x4 acc[2] = {zero4, zero4};

  for (int tk = 0; tk < NKSTEP; ++tk) {
    async16((const char*)Wot + (size_t)tk * 4096 + tid * 16, (char*)sWo + tid * 16);

    int kk = tk >> 2, cc = tk & 3;
    int ky = kk / 3, kx = kk - ky * 3;
#pragma unroll
    for (int half = 0; half < 2; ++half) {
      int row = r0 + half * 32;
      int m_s = tm * 64 + row;
      int b_s = m_s >> 12, hw_s = m_s & 4095, h_s = hw_s >> 6, w_s = hw_s & 63;
      int yy = h_s + ky - 1, xx = w_s + kx - 1;
      bool valid = ((unsigned)yy < 64u) && ((unsigned)xx < 64u);
      short8 h8 = {0, 0, 0, 0, 0, 0, 0, 0};
      if (valid) {
        h8 = *(const short8*)(xTh + ((((size_t)b_s << 12) + yy * 64 + xx) << 8) + cc * 64 + kb);
      }
      *(short8*)&sP[row * 64 + kb] = h8;
    }
    __syncthreads();

    short8 bfr[2], a[2][2];
#pragma unroll
    for (int kc = 0; kc < 2; ++kc) {
      bfr[kc] = *(const short8*)&sP[(wv * 16 + lo) * 64 + kc * 32 + hi * 8];
#pragma unroll
      for (int f = 0; f < 2; ++f)
        a[f][kc] = *(const short8*)&sWo[(f * 16 + lo) * 64 + kc * 32 + hi * 8];
    }
#pragma unroll
    for (int f = 0; f < 2; ++f)
#pragma unroll
      for (int kc = 0; kc < 2; ++kc)
        acc[f] = __builtin_amdgcn_mfma_f32_16x16x32_bf16(a[f][kc], bfr[kc], acc[f], 0, 0, 0);
    __syncthreads();
  }

  int m_o = tm * 64 + wv * 16 + lo;
  int b_o = m_o >> 12, hw_o = m_o & 4095;
#pragma unroll
  for (int f = 0; f < 2; ++f) {
#pragma unroll
    for (int r = 0; r < 4; ++r) {
      int oc = f * 16 + hi * 4 + r;
      if (oc < 27)
        om[(((size_t)(b_o * 27 + oc)) << 12) + hw_o] = acc[f][r] + boff[oc];
    }
  }
}

// ---------------------------------------------------------------------------
// K23: fused deformable-gather + GEMM. 64 m x 256 o per block, grid 256,
// 512 threads (8 waves; wave wv owns o in [wv*32, wv*32+32)).
// Single-buffered LDS (58KB -> 2 blocks/CU), reg-staged W + bf16 taps,
// raw s_barrier + lgkmcnt(0) (no vmcnt drain in loop: prefetch stays in
// flight across barriers, drains at use one phase later).
// ---------------------------------------------------------------------------
__global__ __launch_bounds__(512, 4) void k23_fused(const __hip_bfloat16* __restrict__ xTh,
                                                    const float* __restrict__ om,
                                                    const __hip_bfloat16* __restrict__ Wt2,
                                                    float* __restrict__ out) {
  __shared__ __align__(16) __hip_bfloat16 sW[256 * 64];   // 32 KB
  __shared__ __align__(16) __hip_bfloat16 sV[64 * 64];    // 8 KB
  __shared__ float sw00[576], sw01[576], sw10[576], sw11[576];   // 9.2 KB
  __shared__ int   so00[576], so01[576], so10[576], so11[576];   // 9.2 KB

  int bid = blockIdx.x;
  int tm = ((bid & 7) << 5) | (bid >> 3);   // chunked XCD swizzle
  int tid = threadIdx.x;
  int wv = tid >> 6, lane = tid & 63;
  int lo = lane & 15, hi = lane >> 4;
  int b = tm >> 6;
  int m0 = tm * 64;

  // ---- prologue A: gather params for (kk 0..8) x (row 0..63) ----
  for (int it = tid; it < 576; it += 512) {
    int kk = it >> 6, row = it & 63;
    int m = m0 + row;
    int hw = m & 4095, h = hw >> 6, w = hw & 63;
    const float* omb = om + ((size_t)(b * 27) << 12) + hw;
    float dy = omb[(size_t)(2 * kk) << 12];
    float dx = omb[(size_t)(2 * kk + 1) << 12];
    float mz = omb[(size_t)(18 + kk) << 12];
    int ky = kk / 3, kx = kk - ky * 3;
    float py = dy + (float)(h - 1 + ky);
    float px = dx + (float)(w - 1 + kx);
    float y0f = floorf(py), x0f = floorf(px);
    float wy = py - y0f, wx = px - x0f;
    int y0 = (int)y0f, x0 = (int)x0f;
    bool vy0 = (unsigned)y0 < 64u, vy1 = (unsigned)(y0 + 1) < 64u;
    bool vx0 = (unsigned)x0 < 64u, vx1 = (unsigned)(x0 + 1) < 64u;
    int cy0 = min(max(y0, 0), 63), cy1 = min(max(y0 + 1, 0), 63);
    int cx0 = min(max(x0, 0), 63), cx1 = min(max(x0 + 1, 0), 63);
    float mask = 1.f / (1.f + __expf(-mz));
    sw00[it] = (vy0 && vx0) ? (1.f - wy) * (1.f - wx) * mask : 0.f;
    sw01[it] = (vy0 && vx1) ? (1.f - wy) * wx * mask : 0.f;
    sw10[it] = (vy1 && vx0) ? wy * (1.f - wx) * mask : 0.f;
    sw11[it] = (vy1 && vx1) ? wy * wx * mask : 0.f;
    so00[it] = cy0 * 64 + cx0;
    so01[it] = cy0 * 64 + cx1;
    so10[it] = cy1 * 64 + cx0;
    so11[it] = cy1 * 64 + cx1;
  }
  __syncthreads();   // params visible (one-time full sync)

  const __hip_bfloat16* xb = xTh + (((size_t)b << 12) << 8);
  int vrow = tid >> 3;          // 0..63 (8 threads/row, 8 ch each)
  int chq  = tid & 7;
  int colz = (chq * 8) ^ ((vrow & 7) << 3);

  // ---- prologue B: prefetch W(0) + taps(0) into registers ----
  short8 wr0, wr1, wr2, wr3, t00, t01, t10, t11;
  {
    const char* wsrc = (const char*)Wt2;
    wr0 = *(const short8*)(wsrc + (0 * 512 + tid) * 16);
    wr1 = *(const short8*)(wsrc + (1 * 512 + tid) * 16);
    wr2 = *(const short8*)(wsrc + (2 * 512 + tid) * 16);
    wr3 = *(const short8*)(wsrc + (3 * 512 + tid) * 16);
    int it = vrow;                       // kk=0, cc=0
    const __hip_bfloat16* base = xb + chq * 8;
    t00 = *(const short8*)(base + (size_t)so00[it] * 256);
    t01 = *(const short8*)(base + (size_t)so01[it] * 256);
    t10 = *(const short8*)(base + (size_t)so10[it] * 256);
    t11 = *(const short8*)(base + (size_t)so11[it] * 256);
  }

  f32x4 zero4 = {0.f, 0.f, 0.f, 0.f};
  f32x4 acc[2][4];
#pragma unroll
  for (int fo = 0; fo < 2; ++fo)
#pragma unroll
    for (int fm = 0; fm < 4; ++fm) acc[fo][fm] = zero4;

  for (int tk = 0; tk < NKSTEP; ++tk) {
    if (tk) __builtin_amdgcn_s_barrier();   // (a) all waves done reading LDS

    // (b) commit staged W + V into LDS (vmcnt waits inserted at reg use)
    *(short8*)((char*)sW + (0 * 512 + tid) * 16) = wr0;
    *(short8*)((char*)sW + (1 * 512 + tid) * 16) = wr1;
    *(short8*)((char*)sW + (2 * 512 + tid) * 16) = wr2;
    *(short8*)((char*)sW + (3 * 512 + tid) * 16) = wr3;
    {
      int it = (tk >> 2) * 64 + vrow;
      float a00 = sw00[it], a01 = sw01[it], a10 = sw10[it], a11 = sw11[it];
      __hip_bfloat16 h8[8];
#pragma unroll
      for (int j = 0; j < 8; ++j) {
        float v = a00 * b2f(t00[j]) + a01 * b2f(t01[j])
                + a10 * b2f(t10[j]) + a11 * b2f(t11[j]);
        h8[j] = __float2bfloat16(v);
      }
      *(short8*)&sV[vrow * 64 + colz] = *(const short8*)h8;
    }

    // (c) prefetch tk+1 (stays in flight across the raw barrier)
    if (tk < NKSTEP - 1) {
      const char* wsrc = (const char*)Wt2 + (size_t)(tk + 1) * 32768;
      wr0 = *(const short8*)(wsrc + (0 * 512 + tid) * 16);
      wr1 = *(const short8*)(wsrc + (1 * 512 + tid) * 16);
      wr2 = *(const short8*)(wsrc + (2 * 512 + tid) * 16);
      wr3 = *(const short8*)(wsrc + (3 * 512 + tid) * 16);
      int tkn = tk + 1;
      int itn = (tkn >> 2) * 64 + vrow;
      const __hip_bfloat16* base = xb + (tkn & 3) * 64 + chq * 8;
      t00 = *(const short8*)(base + (size_t)so00[itn] * 256);
      t01 = *(const short8*)(base + (size_t)so01[itn] * 256);
      t10 = *(const short8*)(base + (size_t)so10[itn] * 256);
      t11 = *(const short8*)(base + (size_t)so11[itn] * 256);
    }

    asm volatile("s_waitcnt lgkmcnt(0)" ::: "memory");  // ds_writes committed
    __builtin_amdgcn_s_barrier();                        // (d) tile ready

    // (e) MFMA
#pragma unroll
    for (int kc = 0; kc < 2; ++kc) {
      short8 bv[4], av[2];
#pragma unroll
      for (int fm = 0; fm < 4; ++fm)
        bv[fm] = *(const short8*)&sV[(fm * 16 + lo) * 64
                                     + ((kc * 32 + hi * 8) ^ ((lo & 7) << 3))];
#pragma unroll
      for (int fo = 0; fo < 2; ++fo)
        av[fo] = *(const short8*)&sW[(wv * 32 + fo * 16 + lo) * 64
                                     + ((kc * 32 + hi * 8) ^ ((lo & 7) << 3))];
#pragma unroll
      for (int fo = 0; fo < 2; ++fo)
#pragma unroll
        for (int fm = 0; fm < 4; ++fm)
          acc[fo][fm] = __builtin_amdgcn_mfma_f32_16x16x32_bf16(av[fo], bv[fm], acc[fo][fm], 0, 0, 0);
    }
  }

  // epilogue: C layout col = lane&15 -> m, row = hi*4+r -> o
  int hwbase = m0 & 4095;
#pragma unroll
  for (int fo = 0; fo < 2; ++fo) {
    int o = wv * 32 + fo * 16 + hi * 4;
#pragma unroll
    for (int fm = 0; fm < 4; ++fm) {
      int mloc = hwbase + fm * 16 + lo;
#pragma unroll
      for (int r = 0; r < 4; ++r)
        out[((size_t)(b * 256 + o + r)) * 4096 + mloc] = acc[fo][fm][r];
    }
  }
}

// ---------------------------------------------------------------------------
extern "C" void kernel_launch(void* const* d_in, const int* in_sizes, int n_in,
                              void* d_out, int out_size, void* d_ws, size_t ws_size,
                              hipStream_t stream) {
  (void)in_sizes; (void)n_in; (void)out_size; (void)ws_size;
  const float* x     = (const float*)d_in[0];
  const float* woff  = (const float*)d_in[1];
  const float* boff  = (const float*)d_in[2];
  const float* wconv = (const float*)d_in[3];
  char* ws = (char*)d_ws;
  float* om   = (float*)(ws + OM_OFF);
  __hip_bfloat16* xTh = (__hip_bfloat16*)(ws + XT_OFF);
  __hip_bfloat16* Wt2 = (__hip_bfloat16*)(ws + WT_OFF);
  __hip_bfloat16* Wot = (__hip_bfloat16*)(ws + WOT_OFF);
  float* out = (float*)d_out;

  hipLaunchKernelGGL(k0_wt,     dim3(2304), dim3(256), 0, stream, wconv, Wt2);
  hipLaunchKernelGGL(k0b_wot,   dim3(288),  dim3(256), 0, stream, woff, Wot);
  hipLaunchKernelGGL(kt_xt,     dim3(1024), dim3(256), 0, stream, x, xTh);
  hipLaunchKernelGGL(k1_omgemm, dim3(256),  dim3(256), 0, stream, xTh, Wot, boff, om);
  hipLaunchKernelGGL(k23_fused, dim3(256),  dim3(512), 0, stream, xTh, om, Wt2, out);
}

// Round 10
// 86.970 us; speedup vs baseline: 1.5472x; 1.0385x over previous
//
#include <hip/hip_runtime.h>
#include <hip/hip_bf16.h>

// Problem constants
#define XH   64
#define XW   64
#define CIN  256
#define COUT 256
#define BATCH 4
#define KK9  9
#define M_TOT 16384      // BATCH*XH*XW
#define K_TOT 2304       // KK9*CIN
#define NKSTEP 36        // K_TOT/64

typedef __attribute__((ext_vector_type(8))) short short8;
typedef __attribute__((ext_vector_type(4))) short short4v;
typedef __attribute__((ext_vector_type(4))) float f32x4;

// Workspace layout (bytes)
#define OM_OFF   0
#define OM_BYTES (BATCH*27*4096*4)            // 1,769,472
#define XT_OFF   (OM_OFF + OM_BYTES)
#define XT_BYTES (BATCH*4096*CIN*2)           // 8,388,608 (bf16)
#define WT_OFF   (XT_OFF + XT_BYTES)
#define WT_BYTES (COUT*K_TOT*2)               // 1,179,648  ([tk][256o][64j], XOR-pre-swizzled)
#define WOT_OFF  (WT_OFF + WT_BYTES)
#define WOT_BYTES (36*32*64*2)                // 147,456    ([tk][32oc][64j], XOR-pre-swizzled)

__device__ __forceinline__ void async16(const void* g, void* l) {
  __builtin_amdgcn_global_load_lds((const __attribute__((address_space(1))) void*)g,
                                   (__attribute__((address_space(3))) void*)l,
                                   16, 0, 0);
}

__device__ __forceinline__ float b2f(short s) {
  union { float f; unsigned u; } x;
  x.u = ((unsigned)(unsigned short)s) << 16;
  return x.f;
}

// ---------------------------------------------------------------------------
// K0: w_conv (O,C,3,3) f32 -> Wt2 tiled bf16: [tk(36)][256 o][64 j],
// j = k_local ^ ((o&7)<<3)  (pre-swizzled source; LDS copy stays linear)
// ---------------------------------------------------------------------------
__global__ __launch_bounds__(256) void k0_wt(const float* __restrict__ wconv,
                                             __hip_bfloat16* __restrict__ Wt2) {
  int e = blockIdx.x * 256 + threadIdx.x;      // < 36*16384 = 589824
  int tk = e >> 14;
  int r  = e & 16383;
  int o  = r >> 6, j = r & 63;
  int kl = j ^ ((o & 7) << 3);
  int k  = tk * 64 + kl;
  int kk = k >> 8, c = k & 255;
  float v = wconv[(o * CIN + c) * KK9 + kk];
  Wt2[e] = __float2bfloat16(v);
}

// ---------------------------------------------------------------------------
// K0b: w_off (27,C,3,3) f32 -> Wot tiled bf16: [tk(36)][32 oc][64 j],
// j = k_local ^ ((oc&7)<<3) (pre-swizzled, same pattern as k0)
// ---------------------------------------------------------------------------
__global__ __launch_bounds__(256) void k0b_wot(const float* __restrict__ woff,
                                               __hip_bfloat16* __restrict__ Wot) {
  int e = blockIdx.x * 256 + threadIdx.x;      // < 36*2048 = 73728
  int tk = e >> 11;
  int r  = e & 2047;
  int ocl = r >> 6, j = r & 63;
  int kl = j ^ ((ocl & 7) << 3);
  int k = tk * 64 + kl;
  int kk = k >> 8, c = k & 255;
  float v = (ocl < 27) ? woff[((size_t)(ocl * 256 + c)) * 9 + kk] : 0.f;
  Wot[e] = __float2bfloat16(v);
}

// ---------------------------------------------------------------------------
// KT: transpose x (B,C,H,W) f32 -> xTh[b][hw][c] bf16 (channel-contiguous)
// ---------------------------------------------------------------------------
__global__ __launch_bounds__(256) void kt_xt(const float* __restrict__ x,
                                             __hip_bfloat16* __restrict__ xTh) {
  __shared__ float t[64][65];
  int blk = blockIdx.x;
  int hwg = blk & 63;
  int cg  = (blk >> 6) & 3;
  int b   = blk >> 8;
  int hw0 = hwg * 64, c0 = cg * 64;
  int l = threadIdx.x & 63, q = threadIdx.x >> 6;
  const float* xb = x + ((size_t)(b * 256 + c0) << 12) + hw0;
#pragma unroll
  for (int i = 0; i < 16; ++i) {
    int cl = q * 16 + i;
    t[cl][l] = xb[((size_t)cl << 12) + l];
  }
  __syncthreads();
  __hip_bfloat16* xTb = xTh + (((size_t)b << 12) + hw0) * 256 + c0;
#pragma unroll
  for (int i = 0; i < 16; ++i) {
    int hwl = q * 16 + i;
    xTb[(size_t)hwl * 256 + l] = __float2bfloat16(t[l][hwl]);
  }
}

// ---------------------------------------------------------------------------
// K1: offset conv as MFMA GEMM. 32 m x 32 oc per block, grid 512 (2/CU).
// 256 thr, 4 waves: wave (wr,wc) = (wv>>1, wv&1) owns 16m x 16oc quadrant.
// XOR-swizzled sP/sWo (conflict-free ds_read_b128).
// ---------------------------------------------------------------------------
__global__ __launch_bounds__(256) void k1_omgemm(const __hip_bfloat16* __restrict__ xTh,
                                                 const __hip_bfloat16* __restrict__ Wot,
                                                 const float* __restrict__ boff,
                                                 float* __restrict__ om) {
  __shared__ __align__(16) __hip_bfloat16 sP[32 * 64];    // 4 KB
  __shared__ __align__(16) __hip_bfloat16 sWo[32 * 64];   // 4 KB
  int bid = blockIdx.x;
  int tm = ((bid & 7) << 6) | (bid >> 3);   // chunked XCD swizzle, 0..511
  int tid = threadIdx.x;
  int wv = tid >> 6, lane = tid & 63;
  int lo = lane & 15, hi = lane >> 4;
  int wr = wv >> 1, wc = wv & 1;

  int row = tid >> 3;           // 0..31
  int kb  = (tid & 7) * 8;      // 0..56
  int colz = kb ^ ((row & 7) << 3);

  int m_s = tm * 32 + row;
  int b_s = m_s >> 12, hw_s = m_s & 4095, h_s = hw_s >> 6, w_s = hw_s & 63;

  f32x4 acc = {0.f, 0.f, 0.f, 0.f};

  for (int tk = 0; tk < NKSTEP; ++tk) {
    async16((const char*)Wot + (size_t)tk * 4096 + tid * 16, (char*)sWo + tid * 16);

    int kk = tk >> 2, cc = tk & 3;
    int ky = kk / 3, kx = kk - ky * 3;
    int yy = h_s + ky - 1, xx = w_s + kx - 1;
    bool valid = ((unsigned)yy < 64u) && ((unsigned)xx < 64u);
    short8 h8 = {0, 0, 0, 0, 0, 0, 0, 0};
    if (valid)
      h8 = *(const short8*)(xTh + ((((size_t)b_s << 12) + yy * 64 + xx) << 8) + cc * 64 + kb);
    *(short8*)&sP[row * 64 + colz] = h8;
    __syncthreads();

#pragma unroll
    for (int kc = 0; kc < 2; ++kc) {
      int cz = (kc * 32 + hi * 8) ^ ((lo & 7) << 3);
      short8 bfr = *(const short8*)&sP[(wr * 16 + lo) * 64 + cz];
      short8 a   = *(const short8*)&sWo[(wc * 16 + lo) * 64 + cz];
      acc = __builtin_amdgcn_mfma_f32_16x16x32_bf16(a, bfr, acc, 0, 0, 0);
    }
    __syncthreads();
  }

  int m_o = tm * 32 + wr * 16 + lo;
  int b_o = m_o >> 12, hw_o = m_o & 4095;
#pragma unroll
  for (int r = 0; r < 4; ++r) {
    int oc = wc * 16 + hi * 4 + r;
    if (oc < 27)
      om[(((size_t)(b_o * 27 + oc)) << 12) + hw_o] = acc[r] + boff[oc];
  }
}

// ---------------------------------------------------------------------------
// K23: fused deformable-gather + GEMM. 32 m x 256 o per block, grid 512
// (2 blocks/CU -> cross-block phase overlap). 512 thr (8 waves; wave wv owns
// o in [wv*32, wv*32+32)). Single-buffered LDS (~46KB), reg-staged W + bf16
// taps, raw s_barrier + lgkmcnt (prefetch stays in flight across barriers),
// setprio around MFMA cluster.
// ---------------------------------------------------------------------------
__global__ __launch_bounds__(512, 4) void k23_fused(const __hip_bfloat16* __restrict__ xTh,
                                                    const float* __restrict__ om,
                                                    const __hip_bfloat16* __restrict__ Wt2,
                                                    float* __restrict__ out) {
  __shared__ __align__(16) __hip_bfloat16 sW[256 * 64];   // 32 KB
  __shared__ __align__(16) __hip_bfloat16 sV[32 * 64];    // 4 KB
  __shared__ float sw00[288], sw01[288], sw10[288], sw11[288];   // 4.6 KB
  __shared__ int   so00[288], so01[288], so10[288], so11[288];   // 4.6 KB

  int bid = blockIdx.x;
  int tm = ((bid & 7) << 6) | (bid >> 3);   // chunked XCD swizzle, 0..511
  int tid = threadIdx.x;
  int wv = tid >> 6, lane = tid & 63;
  int lo = lane & 15, hi = lane >> 4;
  int b = tm >> 7;
  int m0 = tm * 32;

  // ---- prologue A: gather params for (kk 0..8) x (row 0..31) ----
  for (int it = tid; it < 288; it += 512) {
    int kk = it >> 5, row = it & 31;
    int m = m0 + row;
    int hw = m & 4095, h = hw >> 6, w = hw & 63;
    const float* omb = om + ((size_t)(b * 27) << 12) + hw;
    float dy = omb[(size_t)(2 * kk) << 12];
    float dx = omb[(size_t)(2 * kk + 1) << 12];
    float mz = omb[(size_t)(18 + kk) << 12];
    int ky = kk / 3, kx = kk - ky * 3;
    float py = dy + (float)(h - 1 + ky);
    float px = dx + (float)(w - 1 + kx);
    float y0f = floorf(py), x0f = floorf(px);
    float wy = py - y0f, wx = px - x0f;
    int y0 = (int)y0f, x0 = (int)x0f;
    bool vy0 = (unsigned)y0 < 64u, vy1 = (unsigned)(y0 + 1) < 64u;
    bool vx0 = (unsigned)x0 < 64u, vx1 = (unsigned)(x0 + 1) < 64u;
    int cy0 = min(max(y0, 0), 63), cy1 = min(max(y0 + 1, 0), 63);
    int cx0 = min(max(x0, 0), 63), cx1 = min(max(x0 + 1, 0), 63);
    float mask = 1.f / (1.f + __expf(-mz));
    sw00[it] = (vy0 && vx0) ? (1.f - wy) * (1.f - wx) * mask : 0.f;
    sw01[it] = (vy0 && vx1) ? (1.f - wy) * wx * mask : 0.f;
    sw10[it] = (vy1 && vx0) ? wy * (1.f - wx) * mask : 0.f;
    sw11[it] = (vy1 && vx1) ? wy * wx * mask : 0.f;
    so00[it] = cy0 * 64 + cx0;
    so01[it] = cy0 * 64 + cx1;
    so10[it] = cy1 * 64 + cx0;
    so11[it] = cy1 * 64 + cx1;
  }
  __syncthreads();   // params visible (one-time full sync)

  const __hip_bfloat16* xb = xTh + ((size_t)b << 20);
  int vrow = tid >> 4;          // 0..31 (16 threads/row, 4 ch each)
  int chq  = tid & 15;
  int colz = (chq * 4) ^ ((vrow & 7) << 3);

  // ---- prologue B: prefetch W(0) + taps(0) into registers ----
  short8 wr0, wr1, wr2, wr3;
  short4v t00, t01, t10, t11;
  {
    const char* wsrc = (const char*)Wt2;
    wr0 = *(const short8*)(wsrc + (0 * 512 + tid) * 16);
    wr1 = *(const short8*)(wsrc + (1 * 512 + tid) * 16);
    wr2 = *(const short8*)(wsrc + (2 * 512 + tid) * 16);
    wr3 = *(const short8*)(wsrc + (3 * 512 + tid) * 16);
    int it = vrow;                       // kk=0, cc=0
    const __hip_bfloat16* base = xb + chq * 4;
    t00 = *(const short4v*)(base + (size_t)so00[it] * 256);
    t01 = *(const short4v*)(base + (size_t)so01[it] * 256);
    t10 = *(const short4v*)(base + (size_t)so10[it] * 256);
    t11 = *(const short4v*)(base + (size_t)so11[it] * 256);
  }

  f32x4 zero4 = {0.f, 0.f, 0.f, 0.f};
  f32x4 acc[2][2];
#pragma unroll
  for (int fo = 0; fo < 2; ++fo)
#pragma unroll
    for (int fm = 0; fm < 2; ++fm) acc[fo][fm] = zero4;

  for (int tk = 0; tk < NKSTEP; ++tk) {
    if (tk) __builtin_amdgcn_s_barrier();   // (a) all waves done reading LDS

    // (b) commit staged W + V into LDS (vmcnt waits inserted at reg use)
    *(short8*)((char*)sW + (0 * 512 + tid) * 16) = wr0;
    *(short8*)((char*)sW + (1 * 512 + tid) * 16) = wr1;
    *(short8*)((char*)sW + (2 * 512 + tid) * 16) = wr2;
    *(short8*)((char*)sW + (3 * 512 + tid) * 16) = wr3;
    {
      int it = (tk >> 2) * 32 + vrow;
      float a00 = sw00[it], a01 = sw01[it], a10 = sw10[it], a11 = sw11[it];
      __hip_bfloat16 h4[4];
#pragma unroll
      for (int j = 0; j < 4; ++j) {
        float v = a00 * b2f(t00[j]) + a01 * b2f(t01[j])
                + a10 * b2f(t10[j]) + a11 * b2f(t11[j]);
        h4[j] = __float2bfloat16(v);
      }
      *(short4v*)&sV[vrow * 64 + colz] = *(const short4v*)h4;
    }

    // (c) prefetch tk+1 (stays in flight across the raw barrier)
    if (tk < NKSTEP - 1) {
      const char* wsrc = (const char*)Wt2 + (size_t)(tk + 1) * 32768;
      wr0 = *(const short8*)(wsrc + (0 * 512 + tid) * 16);
      wr1 = *(const short8*)(wsrc + (1 * 512 + tid) * 16);
      wr2 = *(const short8*)(wsrc + (2 * 512 + tid) * 16);
      wr3 = *(const short8*)(wsrc + (3 * 512 + tid) * 16);
      int tkn = tk + 1;
      int itn = (tkn >> 2) * 32 + vrow;
      const __hip_bfloat16* base = xb + (tkn & 3) * 64 + chq * 4;
      t00 = *(const short4v*)(base + (size_t)so00[itn] * 256);
      t01 = *(const short4v*)(base + (size_t)so01[itn] * 256);
      t10 = *(const short4v*)(base + (size_t)so10[itn] * 256);
      t11 = *(const short4v*)(base + (size_t)so11[itn] * 256);
    }

    asm volatile("s_waitcnt lgkmcnt(0)" ::: "memory");  // ds_writes committed
    __builtin_amdgcn_s_barrier();                        // (d) tile ready

    // (e) MFMA cluster
    __builtin_amdgcn_s_setprio(1);
#pragma unroll
    for (int kc = 0; kc < 2; ++kc) {
      int cz = (kc * 32 + hi * 8) ^ ((lo & 7) << 3);
      short8 bv[2], av[2];
#pragma unroll
      for (int fm = 0; fm < 2; ++fm)
        bv[fm] = *(const short8*)&sV[(fm * 16 + lo) * 64 + cz];
#pragma unroll
      for (int fo = 0; fo < 2; ++fo)
        av[fo] = *(const short8*)&sW[(wv * 32 + fo * 16 + lo) * 64 + cz];
#pragma unroll
      for (int fo = 0; fo < 2; ++fo)
#pragma unroll
        for (int fm = 0; fm < 2; ++fm)
          acc[fo][fm] = __builtin_amdgcn_mfma_f32_16x16x32_bf16(av[fo], bv[fm], acc[fo][fm], 0, 0, 0);
    }
    __builtin_amdgcn_s_setprio(0);
  }

  // epilogue: C layout col = lane&15 -> m, row = hi*4+r -> o
  int hwbase = m0 & 4095;
#pragma unroll
  for (int fo = 0; fo < 2; ++fo) {
    int o = wv * 32 + fo * 16 + hi * 4;
#pragma unroll
    for (int fm = 0; fm < 2; ++fm) {
      int mloc = hwbase + fm * 16 + lo;
#pragma unroll
      for (int r = 0; r < 4; ++r)
        out[((size_t)(b * 256 + o + r)) * 4096 + mloc] = acc[fo][fm][r];
    }
  }
}

// ---------------------------------------------------------------------------
extern "C" void kernel_launch(void* const* d_in, const int* in_sizes, int n_in,
                              void* d_out, int out_size, void* d_ws, size_t ws_size,
                              hipStream_t stream) {
  (void)in_sizes; (void)n_in; (void)out_size; (void)ws_size;
  const float* x     = (const float*)d_in[0];
  const float* woff  = (const float*)d_in[1];
  const float* boff  = (const float*)d_in[2];
  const float* wconv = (const float*)d_in[3];
  char* ws = (char*)d_ws;
  float* om   = (float*)(ws + OM_OFF);
  __hip_bfloat16* xTh = (__hip_bfloat16*)(ws + XT_OFF);
  __hip_bfloat16* Wt2 = (__hip_bfloat16*)(ws + WT_OFF);
  __hip_bfloat16* Wot = (__hip_bfloat16*)(ws + WOT_OFF);
  float* out = (float*)d_out;

  hipLaunchKernelGGL(k0_wt,     dim3(2304), dim3(256), 0, stream, wconv, Wt2);
  hipLaunchKernelGGL(k0b_wot,   dim3(288),  dim3(256), 0, stream, woff, Wot);
  hipLaunchKernelGGL(kt_xt,     dim3(1024), dim3(256), 0, stream, x, xTh);
  hipLaunchKernelGGL(k1_omgemm, dim3(512),  dim3(256), 0, stream, xTh, Wot, boff, om);
  hipLaunchKernelGGL(k23_fused, dim3(512),  dim3(512), 0, stream, xTh, om, Wt2, out);
}

// Round 11
// 77.503 us; speedup vs baseline: 1.7361x; 1.1221x over previous
//
#include <hip/hip_runtime.h>
#include <hip/hip_bf16.h>

// Problem constants
#define XH   64
#define XW   64
#define CIN  256
#define COUT 256
#define BATCH 4
#define KK9  9
#define M_TOT 16384      // BATCH*XH*XW
#define K_TOT 2304       // KK9*CIN
#define NKSTEP 36        // K_TOT/64

typedef __attribute__((ext_vector_type(8))) short short8;
typedef __attribute__((ext_vector_type(4))) short short4v;
typedef __attribute__((ext_vector_type(4))) float f32x4;

// Workspace layout (bytes)
#define OM_OFF   0
#define OM_BYTES (BATCH*27*4096*4)            // 1,769,472
#define XT_OFF   (OM_OFF + OM_BYTES)
#define XT_BYTES (BATCH*4096*CIN*2)           // 8,388,608 (bf16)
#define WT_OFF   (XT_OFF + XT_BYTES)
#define WT_BYTES (COUT*K_TOT*2)               // 1,179,648  ([tk][256o][64j], XOR-pre-swizzled)
#define WOT_OFF  (WT_OFF + WT_BYTES)
#define WOT_BYTES (36*32*64*2)                // 147,456    ([tk][32oc][64j], XOR-pre-swizzled)

__device__ __forceinline__ void async16(const void* g, void* l) {
  __builtin_amdgcn_global_load_lds((const __attribute__((address_space(1))) void*)g,
                                   (__attribute__((address_space(3))) void*)l,
                                   16, 0, 0);
}

__device__ __forceinline__ float b2f(short s) {
  union { float f; unsigned u; } x;
  x.u = ((unsigned)(unsigned short)s) << 16;
  return x.f;
}

// ---------------------------------------------------------------------------
// K0: w_conv (O,C,3,3) f32 -> Wt2 tiled bf16: [tk(36)][256 o][64 j],
// j = k_local ^ ((o&7)<<3)  (pre-swizzled source; LDS copy stays linear)
// ---------------------------------------------------------------------------
__global__ __launch_bounds__(256) void k0_wt(const float* __restrict__ wconv,
                                             __hip_bfloat16* __restrict__ Wt2) {
  int e = blockIdx.x * 256 + threadIdx.x;      // < 36*16384 = 589824
  int tk = e >> 14;
  int r  = e & 16383;
  int o  = r >> 6, j = r & 63;
  int kl = j ^ ((o & 7) << 3);
  int k  = tk * 64 + kl;
  int kk = k >> 8, c = k & 255;
  float v = wconv[(o * CIN + c) * KK9 + kk];
  Wt2[e] = __float2bfloat16(v);
}

// ---------------------------------------------------------------------------
// K0b: w_off (27,C,3,3) f32 -> Wot tiled bf16: [tk(36)][32 oc][64 j],
// j = k_local ^ ((oc&7)<<3)
// ---------------------------------------------------------------------------
__global__ __launch_bounds__(256) void k0b_wot(const float* __restrict__ woff,
                                               __hip_bfloat16* __restrict__ Wot) {
  int e = blockIdx.x * 256 + threadIdx.x;      // < 36*2048 = 73728
  int tk = e >> 11;
  int r  = e & 2047;
  int ocl = r >> 6, j = r & 63;
  int kl = j ^ ((ocl & 7) << 3);
  int k = tk * 64 + kl;
  int kk = k >> 8, c = k & 255;
  float v = (ocl < 27) ? woff[((size_t)(ocl * 256 + c)) * 9 + kk] : 0.f;
  Wot[e] = __float2bfloat16(v);
}

// ---------------------------------------------------------------------------
// KT: transpose x (B,C,H,W) f32 -> xTh[b][hw][c] bf16 (channel-contiguous)
// ---------------------------------------------------------------------------
__global__ __launch_bounds__(256) void kt_xt(const float* __restrict__ x,
                                             __hip_bfloat16* __restrict__ xTh) {
  __shared__ float t[64][65];
  int blk = blockIdx.x;
  int hwg = blk & 63;
  int cg  = (blk >> 6) & 3;
  int b   = blk >> 8;
  int hw0 = hwg * 64, c0 = cg * 64;
  int l = threadIdx.x & 63, q = threadIdx.x >> 6;
  const float* xb = x + ((size_t)(b * 256 + c0) << 12) + hw0;
#pragma unroll
  for (int i = 0; i < 16; ++i) {
    int cl = q * 16 + i;
    t[cl][l] = xb[((size_t)cl << 12) + l];
  }
  __syncthreads();
  __hip_bfloat16* xTb = xTh + (((size_t)b << 12) + hw0) * 256 + c0;
#pragma unroll
  for (int i = 0; i < 16; ++i) {
    int hwl = q * 16 + i;
    xTb[(size_t)hwl * 256 + l] = __float2bfloat16(t[l][hwl]);
  }
}

// ---------------------------------------------------------------------------
// K1: offset conv as MFMA GEMM. 32 m x 32 oc per block, grid 512 (2/CU).
// ---------------------------------------------------------------------------
__global__ __launch_bounds__(256) void k1_omgemm(const __hip_bfloat16* __restrict__ xTh,
                                                 const __hip_bfloat16* __restrict__ Wot,
                                                 const float* __restrict__ boff,
                                                 float* __restrict__ om) {
  __shared__ __align__(16) __hip_bfloat16 sP[32 * 64];    // 4 KB
  __shared__ __align__(16) __hip_bfloat16 sWo[32 * 64];   // 4 KB
  int bid = blockIdx.x;
  int tm = ((bid & 7) << 6) | (bid >> 3);   // chunked XCD swizzle, 0..511
  int tid = threadIdx.x;
  int wv = tid >> 6, lane = tid & 63;
  int lo = lane & 15, hi = lane >> 4;
  int wr = wv >> 1, wc = wv & 1;

  int row = tid >> 3;           // 0..31
  int kb  = (tid & 7) * 8;      // 0..56
  int colz = kb ^ ((row & 7) << 3);

  int m_s = tm * 32 + row;
  int b_s = m_s >> 12, hw_s = m_s & 4095, h_s = hw_s >> 6, w_s = hw_s & 63;

  f32x4 acc = {0.f, 0.f, 0.f, 0.f};

  for (int tk = 0; tk < NKSTEP; ++tk) {
    async16((const char*)Wot + (size_t)tk * 4096 + tid * 16, (char*)sWo + tid * 16);

    int kk = tk >> 2, cc = tk & 3;
    int ky = kk / 3, kx = kk - ky * 3;
    int yy = h_s + ky - 1, xx = w_s + kx - 1;
    bool valid = ((unsigned)yy < 64u) && ((unsigned)xx < 64u);
    short8 h8 = {0, 0, 0, 0, 0, 0, 0, 0};
    if (valid)
      h8 = *(const short8*)(xTh + ((((size_t)b_s << 12) + yy * 64 + xx) << 8) + cc * 64 + kb);
    *(short8*)&sP[row * 64 + colz] = h8;
    __syncthreads();

#pragma unroll
    for (int kc = 0; kc < 2; ++kc) {
      int cz = (kc * 32 + hi * 8) ^ ((lo & 7) << 3);
      short8 bfr = *(const short8*)&sP[(wr * 16 + lo) * 64 + cz];
      short8 a   = *(const short8*)&sWo[(wc * 16 + lo) * 64 + cz];
      acc = __builtin_amdgcn_mfma_f32_16x16x32_bf16(a, bfr, acc, 0, 0, 0);
    }
    __syncthreads();
  }

  int m_o = tm * 32 + wr * 16 + lo;
  int b_o = m_o >> 12, hw_o = m_o & 4095;
#pragma unroll
  for (int r = 0; r < 4; ++r) {
    int oc = wc * 16 + hi * 4 + r;
    if (oc < 27)
      om[(((size_t)(b_o * 27 + oc)) << 12) + hw_o] = acc[r] + boff[oc];
  }
}

// ---------------------------------------------------------------------------
// K23: fused deformable-gather + GEMM. 64 m x 256 o per block, grid 256,
// 512 thr (8 waves; wave wv owns o in [wv*32, wv*32+32)).
// W: global_load_lds DMA into DOUBLE-buffered sW, issued one K-step ahead,
//    never vmcnt-drained in the loop (tap loads issued after the W-DMA each
//    step; in-order vmcnt retirement means the compiler's automatic wait on
//    tap registers implies the prior W-DMA has landed).
// V: reg-staged bf16 taps -> VALU bilinear -> single sV.
// Raw s_barrier + lgkmcnt only. XOR-swizzled LDS (0 conflicts).
// ---------------------------------------------------------------------------
__global__ __launch_bounds__(512, 4) void k23_fused(const __hip_bfloat16* __restrict__ xTh,
                                                    const float* __restrict__ om,
                                                    const __hip_bfloat16* __restrict__ Wt2,
                                                    float* __restrict__ out) {
  __shared__ __align__(16) __hip_bfloat16 sW[2][256 * 64];   // 64 KB
  __shared__ __align__(16) __hip_bfloat16 sV[64 * 64];       // 8 KB
  __shared__ float sw00[576], sw01[576], sw10[576], sw11[576];   // 9.2 KB
  __shared__ int   so00[576], so01[576], so10[576], so11[576];   // 9.2 KB

  int bid = blockIdx.x;
  int tm = ((bid & 7) << 5) | (bid >> 3);   // chunked XCD swizzle, 0..255
  int tid = threadIdx.x;
  int wv = tid >> 6, lane = tid & 63;
  int lo = lane & 15, hi = lane >> 4;
  int b = tm >> 6;
  int m0 = tm * 64;

  // ---- prologue A: gather params for (kk 0..8) x (row 0..63) ----
  for (int it = tid; it < 576; it += 512) {
    int kk = it >> 6, row = it & 63;
    int m = m0 + row;
    int hw = m & 4095, h = hw >> 6, w = hw & 63;
    const float* omb = om + ((size_t)(b * 27) << 12) + hw;
    float dy = omb[(size_t)(2 * kk) << 12];
    float dx = omb[(size_t)(2 * kk + 1) << 12];
    float mz = omb[(size_t)(18 + kk) << 12];
    int ky = kk / 3, kx = kk - ky * 3;
    float py = dy + (float)(h - 1 + ky);
    float px = dx + (float)(w - 1 + kx);
    float y0f = floorf(py), x0f = floorf(px);
    float wy = py - y0f, wx = px - x0f;
    int y0 = (int)y0f, x0 = (int)x0f;
    bool vy0 = (unsigned)y0 < 64u, vy1 = (unsigned)(y0 + 1) < 64u;
    bool vx0 = (unsigned)x0 < 64u, vx1 = (unsigned)(x0 + 1) < 64u;
    int cy0 = min(max(y0, 0), 63), cy1 = min(max(y0 + 1, 0), 63);
    int cx0 = min(max(x0, 0), 63), cx1 = min(max(x0 + 1, 0), 63);
    float mask = 1.f / (1.f + __expf(-mz));
    sw00[it] = (vy0 && vx0) ? (1.f - wy) * (1.f - wx) * mask : 0.f;
    sw01[it] = (vy0 && vx1) ? (1.f - wy) * wx * mask : 0.f;
    sw10[it] = (vy1 && vx0) ? wy * (1.f - wx) * mask : 0.f;
    sw11[it] = (vy1 && vx1) ? wy * wx * mask : 0.f;
    so00[it] = cy0 * 64 + cx0;
    so01[it] = cy0 * 64 + cx1;
    so10[it] = cy1 * 64 + cx0;
    so11[it] = cy1 * 64 + cx1;
  }
  __syncthreads();   // params visible (one-time full sync)

  const __hip_bfloat16* xb = xTh + ((size_t)b << 20);
  int vrow = tid >> 3;          // 0..63 (8 threads/row, 8 ch each)
  int chq  = tid & 7;
  int colz = (chq * 8) ^ ((vrow & 7) << 3);

  // ---- prologue B: W(0) DMA -> sW[0]; taps(0) -> regs (AFTER the DMA) ----
  short8 t00, t01, t10, t11;
  {
#pragma unroll
    for (int j = 0; j < 4; ++j) {
      int off = (j * 512 + tid) * 16;
      async16((const char*)Wt2 + off, (char*)sW[0] + off);
    }
    int it = vrow;                       // kk=0, cc=0
    const __hip_bfloat16* base = xb + chq * 8;
    t00 = *(const short8*)(base + (size_t)so00[it] * 256);
    t01 = *(const short8*)(base + (size_t)so01[it] * 256);
    t10 = *(const short8*)(base + (size_t)so10[it] * 256);
    t11 = *(const short8*)(base + (size_t)so11[it] * 256);
  }

  f32x4 zero4 = {0.f, 0.f, 0.f, 0.f};
  f32x4 acc[2][4];
#pragma unroll
  for (int fo = 0; fo < 2; ++fo)
#pragma unroll
    for (int fm = 0; fm < 4; ++fm) acc[fo][fm] = zero4;

  for (int tk = 0; tk < NKSTEP; ++tk) {
    int cb = tk & 1, nb = cb ^ 1;
    if (tk) __builtin_amdgcn_s_barrier();   // (a) all waves done reading LDS

    // (b) V-commit: auto vmcnt wait on tap regs => W(tk) DMA also retired
    {
      int it = (tk >> 2) * 64 + vrow;
      float a00 = sw00[it], a01 = sw01[it], a10 = sw10[it], a11 = sw11[it];
      __hip_bfloat16 h8[8];
#pragma unroll
      for (int j = 0; j < 8; ++j) {
        float v = a00 * b2f(t00[j]) + a01 * b2f(t01[j])
                + a10 * b2f(t10[j]) + a11 * b2f(t11[j]);
        h8[j] = __float2bfloat16(v);
      }
      *(short8*)&sV[vrow * 64 + colz] = *(const short8*)h8;
    }

    // (c) prefetch tk+1: W-DMA first, taps after (ordering carries the wait)
    if (tk < NKSTEP - 1) {
#pragma unroll
      for (int j = 0; j < 4; ++j) {
        int off = (j * 512 + tid) * 16;
        async16((const char*)Wt2 + (size_t)(tk + 1) * 32768 + off, (char*)sW[nb] + off);
      }
      int tkn = tk + 1;
      int itn = (tkn >> 2) * 64 + vrow;
      const __hip_bfloat16* base = xb + (tkn & 3) * 64 + chq * 8;
      t00 = *(const short8*)(base + (size_t)so00[itn] * 256);
      t01 = *(const short8*)(base + (size_t)so01[itn] * 256);
      t10 = *(const short8*)(base + (size_t)so10[itn] * 256);
      t11 = *(const short8*)(base + (size_t)so11[itn] * 256);
    }

    asm volatile("s_waitcnt lgkmcnt(0)" ::: "memory");  // V ds_write committed
    __builtin_amdgcn_s_barrier();                        // (d) tile ready

    // (e) MFMA cluster on sW[cb] + sV
    __builtin_amdgcn_s_setprio(1);
#pragma unroll
    for (int kc = 0; kc < 2; ++kc) {
      int cz = (kc * 32 + hi * 8) ^ ((lo & 7) << 3);
      short8 bv[4], av[2];
#pragma unroll
      for (int fm = 0; fm < 4; ++fm)
        bv[fm] = *(const short8*)&sV[(fm * 16 + lo) * 64 + cz];
#pragma unroll
      for (int fo = 0; fo < 2; ++fo)
        av[fo] = *(const short8*)&sW[cb][(wv * 32 + fo * 16 + lo) * 64 + cz];
#pragma unroll
      for (int fo = 0; fo < 2; ++fo)
#pragma unroll
        for (int fm = 0; fm < 4; ++fm)
          acc[fo][fm] = __builtin_amdgcn_mfma_f32_16x16x32_bf16(av[fo], bv[fm], acc[fo][fm], 0, 0, 0);
    }
    __builtin_amdgcn_s_setprio(0);
  }

  // epilogue: C layout col = lane&15 -> m, row = hi*4+r -> o
  int hwbase = m0 & 4095;
#pragma unroll
  for (int fo = 0; fo < 2; ++fo) {
    int o = wv * 32 + fo * 16 + hi * 4;
#pragma unroll
    for (int fm = 0; fm < 4; ++fm) {
      int mloc = hwbase + fm * 16 + lo;
#pragma unroll
      for (int r = 0; r < 4; ++r)
        out[((size_t)(b * 256 + o + r)) * 4096 + mloc] = acc[fo][fm][r];
    }
  }
}

// ---------------------------------------------------------------------------
extern "C" void kernel_launch(void* const* d_in, const int* in_sizes, int n_in,
                              void* d_out, int out_size, void* d_ws, size_t ws_size,
                              hipStream_t stream) {
  (void)in_sizes; (void)n_in; (void)out_size; (void)ws_size;
  const float* x     = (const float*)d_in[0];
  const float* woff  = (const float*)d_in[1];
  const float* boff  = (const float*)d_in[2];
  const float* wconv = (const float*)d_in[3];
  char* ws = (char*)d_ws;
  float* om   = (float*)(ws + OM_OFF);
  __hip_bfloat16* xTh = (__hip_bfloat16*)(ws + XT_OFF);
  __hip_bfloat16* Wt2 = (__hip_bfloat16*)(ws + WT_OFF);
  __hip_bfloat16* Wot = (__hip_bfloat16*)(ws + WOT_OFF);
  float* out = (float*)d_out;

  hipLaunchKernelGGL(k0_wt,     dim3(2304), dim3(256), 0, stream, wconv, Wt2);
  hipLaunchKernelGGL(k0b_wot,   dim3(288),  dim3(256), 0, stream, woff, Wot);
  hipLaunchKernelGGL(kt_xt,     dim3(1024), dim3(256), 0, stream, x, xTh);
  hipLaunchKernelGGL(k1_omgemm, dim3(512),  dim3(256), 0, stream, xTh, Wot, boff, om);
  hipLaunchKernelGGL(k23_fused, dim3(256),  dim3(512), 0, stream, xTh, om, Wt2, out);
}